// Round 4
// baseline (2358.213 us; speedup 1.0000x reference)
//
#include <hip/hip_runtime.h>

typedef __attribute__((ext_vector_type(8))) short short8;
typedef __attribute__((ext_vector_type(4))) float f32x4;
typedef __attribute__((ext_vector_type(4))) unsigned int u32x4;

#define DEV static __device__ __forceinline__

DEV unsigned short f2bf(float f){
  unsigned int u = __float_as_uint(f);
  u += 0x7FFFu + ((u >> 16) & 1u);
  return (unsigned short)(u >> 16);
}
DEV float bf2f(unsigned short h){ return __uint_as_float(((unsigned int)h) << 16); }

#define DTM 0.1f   /* DT*TAU_MEM_INV */
#define SYN 0.8f   /* 1 - DT*TAU_SYN_INV */
#define VTH 0.2f

// ---------------------------------------------------------------------------
// prep: build [tap][co][ci] bf16 hi/mid/lo weight digits, zero conv4 partial.
// ---------------------------------------------------------------------------
__global__ __launch_bounds__(256) void prep_kernel(
    const float* __restrict__ w2, const float* __restrict__ w3, const float* __restrict__ w4,
    unsigned short* __restrict__ wb2h, unsigned short* __restrict__ wb2m, unsigned short* __restrict__ wb2l,
    unsigned short* __restrict__ wb3h, unsigned short* __restrict__ wb3m, unsigned short* __restrict__ wb3l,
    unsigned short* __restrict__ wb4h, unsigned short* __restrict__ wb4m, unsigned short* __restrict__ wb4l,
    float* __restrict__ partial)
{
  const int N2 = 9*128*64, N3 = 9*256*128, N4 = 9*256*256, NP = 2048*256;
  int tid = blockIdx.x*256 + threadIdx.x;
  if (tid < N2) {
    int tap = tid/(128*64), r = tid%(128*64), co = r>>6, ci = r&63;
    float w = w2[(co*64+ci)*9 + tap];
    unsigned short h = f2bf(w);       float r1 = w - bf2f(h);
    unsigned short m = f2bf(r1);      float r2 = r1 - bf2f(m);
    wb2h[tid] = h; wb2m[tid] = m; wb2l[tid] = f2bf(r2);
    return;
  }
  tid -= N2;
  if (tid < N3) {
    int tap = tid/(256*128), r = tid%(256*128), co = r>>7, ci = r&127;
    float w = w3[(co*128+ci)*9 + tap];
    unsigned short h = f2bf(w);       float r1 = w - bf2f(h);
    unsigned short m = f2bf(r1);      float r2 = r1 - bf2f(m);
    wb3h[tid] = h; wb3m[tid] = m; wb3l[tid] = f2bf(r2);
    return;
  }
  tid -= N3;
  if (tid < N4) {
    int tap = tid/(256*256), r = tid%(256*256), co = r>>8, ci = r&255;
    float w = w4[(co*256+ci)*9 + tap];
    unsigned short h = f2bf(w);       float r1 = w - bf2f(h);
    unsigned short m = f2bf(r1);      float r2 = r1 - bf2f(m);
    wb4h[tid] = h; wb4m[tid] = m; wb4l[tid] = f2bf(r2);
    return;
  }
  tid -= N4;
  if (tid < NP) partial[tid] = 0.f;
}

// ---------------------------------------------------------------------------
// K1: conv1 (fp32 direct, 3->64, 3x3 SAME) + LIF1. grid 512 = 32 imgs x 16 row-pairs
// ---------------------------------------------------------------------------
__global__ __launch_bounds__(256) void k1_conv1_lif(
    const float* __restrict__ x, const float* __restrict__ w1,
    float* __restrict__ v1, float* __restrict__ i1,
    unsigned short* __restrict__ z1, int t)
{
  __shared__ float xs[3][4][34];
  __shared__ float wl[27][64];
  int tid = threadIdx.x;
  int b = blockIdx.x >> 4, y0 = (blockIdx.x & 15) * 2;
  for (int e = tid; e < 3*4*34; e += 256) {
    int ci = e/136, r2 = e%136, r = r2/34, xi = r2%34;
    int y = y0 - 1 + r, xg = xi - 1;
    float v = 0.f;
    if (y >= 0 && y < 32 && xg >= 0 && xg < 32)
      v = x[((t*32 + b)*3 + ci)*1024 + y*32 + xg];
    xs[ci][r][xi] = v;
  }
  for (int e = tid; e < 27*64; e += 256) {
    int row = e >> 6, co = e & 63;
    int ci = row % 3, tap = row / 3, ky = tap/3, kx = tap%3;
    wl[row][co] = w1[((co*3+ci)*3+ky)*3+kx];
  }
  __syncthreads();
  int px = tid >> 2, cg = tid & 3;
  int ly = px >> 5, lx = px & 31;
  float acc[16];
#pragma unroll
  for (int q = 0; q < 16; q++) acc[q] = 0.f;
#pragma unroll
  for (int ky = 0; ky < 3; ky++)
#pragma unroll
    for (int kx = 0; kx < 3; kx++)
#pragma unroll
      for (int ci = 0; ci < 3; ci++) {
        float xv = xs[ci][ly+ky][lx+kx];
        const float4* wr = (const float4*)&wl[(ky*3+kx)*3+ci][cg*16];
#pragma unroll
        for (int q = 0; q < 4; q++) {
          float4 w4 = wr[q];
          acc[q*4+0] = fmaf(xv, w4.x, acc[q*4+0]);
          acc[q*4+1] = fmaf(xv, w4.y, acc[q*4+1]);
          acc[q*4+2] = fmaf(xv, w4.z, acc[q*4+2]);
          acc[q*4+3] = fmaf(xv, w4.w, acc[q*4+3]);
        }
      }
  int m_g = b*1024 + (y0+ly)*32 + lx;
  unsigned short zb[16];
#pragma unroll
  for (int q = 0; q < 4; q++) {
    int idx = m_g*64 + cg*16 + q*4;
    float vv[4] = {0.f,0.f,0.f,0.f}, ii[4] = {0.f,0.f,0.f,0.f};
    if (t != 0) {
      float4 v4 = *(const float4*)(v1+idx); float4 i4 = *(const float4*)(i1+idx);
      vv[0]=v4.x; vv[1]=v4.y; vv[2]=v4.z; vv[3]=v4.w;
      ii[0]=i4.x; ii[1]=i4.y; ii[2]=i4.z; ii[3]=i4.w;
    }
#pragma unroll
    for (int s = 0; s < 4; s++) {
      float vdec = vv[s] + DTM*((0.0f - vv[s]) + ii[s]);
      bool z = (vdec - VTH) > 0.0f;
      vv[s] = z ? 0.0f : vdec;
      ii[s] = SYN*ii[s] + acc[q*4+s];
      zb[q*4+s] = z ? 0x3F80 : 0;
    }
    *(float4*)(v1+idx) = make_float4(vv[0],vv[1],vv[2],vv[3]);
    *(float4*)(i1+idx) = make_float4(ii[0],ii[1],ii[2],ii[3]);
  }
  u32x4 za, zc;
  za[0]=zb[0]|((unsigned)zb[1]<<16); za[1]=zb[2]|((unsigned)zb[3]<<16);
  za[2]=zb[4]|((unsigned)zb[5]<<16); za[3]=zb[6]|((unsigned)zb[7]<<16);
  zc[0]=zb[8]|((unsigned)zb[9]<<16); zc[1]=zb[10]|((unsigned)zb[11]<<16);
  zc[2]=zb[12]|((unsigned)zb[13]<<16); zc[3]=zb[14]|((unsigned)zb[15]<<16);
  *(u32x4*)(z1 + m_g*64 + cg*16) = za;
  *(u32x4*)(z1 + m_g*64 + cg*16 + 8) = zc;
}

// ---------------------------------------------------------------------------
// Implicit-GEMM conv (3x3 SAME) over binary spikes, bf16 hi/mid/lo 3-digit
// MFMA. A staged once in LDS (XOR-swizzled); B fragments loaded per-lane
// DIRECTLY from global (L2) -- K-loop is barrier-free.
// Epilogue: fused LIF + (POOLZ) 2x2 max-pool of spikes via LDS OR-reduce,
// or (KSPLIT) atomic partial accumulation (exactly 2 adds/elem: deterministic).
// ---------------------------------------------------------------------------
template<int MF, int NF, int WM, int WN, int CIN_A, int WI, int HIM,
         int COUT, int CIN_SRC, int NT, bool KSPLIT, bool POOLZ>
__global__ __launch_bounds__(WM*WN*64, 1) void conv_lif(
    const unsigned short* __restrict__ zsrc,
    const unsigned short* __restrict__ wbh, const unsigned short* __restrict__ wbm,
    const unsigned short* __restrict__ wbl,
    float* __restrict__ vst, float* __restrict__ ist,
    unsigned short* __restrict__ zpool, float* __restrict__ partial, int t)
{
  constexpr int THREADS = WM*WN*64;
  constexpr int BM = WM*MF*16;
  constexpr int BN = WN*NF*16;
  constexpr int ROWS = BM/WI;
  constexpr int SLOTW = WI+2;
  constexpr int SLOTS = (ROWS+2)*SLOTW;
  constexpr int CPH = CIN_A/64;
  constexpr int P = 9*CPH;
  constexpr int MT_PER_B = (HIM*WI)/BM;
  constexpr int ACH = CIN_A/8;
  constexpr int ACHUNKS = SLOTS*ACH;
  constexpr int LDS_A = SLOTS*CIN_A*2;
  constexpr int LDS_Z = POOLZ ? BM*BN*2 : 16;
  constexpr int LDS_SZ = LDS_A > LDS_Z ? LDS_A : LDS_Z;
  static_assert(LDS_SZ <= 48*1024, "LDS");

  __shared__ __align__(16) char smem[LDS_SZ];

  int tid = threadIdx.x;
  int rem = blockIdx.x;
  int kh = 0;
  if constexpr (KSPLIT) { kh = rem & 1; rem >>= 1; }
  int nt = 0;
  if constexpr (NT > 1) { nt = rem % NT; rem /= NT; }
  int b = rem / MT_PER_B;
  int y0 = (rem % MT_PER_B) * ROWS;
  int lane = tid & 63;
  int wv = tid >> 6, wn = wv % WN, wm = wv / WN;
  int klane = (lane >> 4) * 8;
  int csrc0 = KSPLIT ? kh*128 : 0;

  // ---- stage A tile (once; t-invariant addresses) ----
  for (int ch = tid; ch < ACHUNKS; ch += THREADS) {
    int slot = ch / ACH, g = ch % ACH;
    int yr = slot / SLOTW, xr = slot % SLOTW;
    int y = y0 + yr - 1, xg = xr - 1;
    u32x4 val; val[0]=0; val[1]=0; val[2]=0; val[3]=0;
    if (y >= 0 && y < HIM && xg >= 0 && xg < WI)
      val = *(const u32x4*)(zsrc + ((long)(b*HIM + y)*WI + xg)*CIN_SRC + csrc0 + g*8);
    int addr = ((slot*CIN_A + g*8)*2) ^ ((slot & 7) << 4);
    *(u32x4*)(smem + addr) = val;
  }

  f32x4 acc[MF][NF];
#pragma unroll
  for (int mf = 0; mf < MF; mf++)
#pragma unroll
    for (int nf = 0; nf < NF; nf++) {
      acc[mf][nf][0]=0.f; acc[mf][nf][1]=0.f; acc[mf][nf][2]=0.f; acc[mf][nf][3]=0.f;
    }

  int grow0 = nt*BN + wn*NF*16 + (lane & 15);
  __syncthreads();

  // ---- barrier-free K loop ----
#pragma unroll 2
  for (int p = 0; p < P; p++) {
    int tap = p / CPH, cs = p % CPH;
    int dy = tap/3 - 1, dx = tap%3 - 1;
#pragma unroll
    for (int ks = 0; ks < 2; ks++) {
      short8 bh[NF], bm_[NF], bl[NF];
#pragma unroll
      for (int nf = 0; nf < NF; nf++) {
        long bo = ((long)tap*COUT + grow0 + nf*16)*CIN_SRC + csrc0 + cs*64 + ks*32 + klane;
        bh[nf]  = *(const short8*)(wbh + bo);
        bm_[nf] = *(const short8*)(wbm + bo);
        bl[nf]  = *(const short8*)(wbl + bo);
      }
      short8 a[MF];
#pragma unroll
      for (int mf = 0; mf < MF; mf++) {
        int pl = wm*MF*16 + mf*16 + (lane & 15);
        int yl = pl / WI, xl = pl % WI;
        int slot = (yl + dy + 1)*SLOTW + (xl + dx + 1);
        int addr = ((slot*CIN_A + cs*64 + ks*32 + klane)*2) ^ ((slot & 7) << 4);
        a[mf] = *(const short8*)(smem + addr);
      }
#pragma unroll
      for (int mf = 0; mf < MF; mf++)
#pragma unroll
        for (int nf = 0; nf < NF; nf++)
          acc[mf][nf] = __builtin_amdgcn_mfma_f32_16x16x32_bf16(a[mf], bh[nf], acc[mf][nf], 0, 0, 0);
#pragma unroll
      for (int mf = 0; mf < MF; mf++)
#pragma unroll
        for (int nf = 0; nf < NF; nf++)
          acc[mf][nf] = __builtin_amdgcn_mfma_f32_16x16x32_bf16(a[mf], bm_[nf], acc[mf][nf], 0, 0, 0);
#pragma unroll
      for (int mf = 0; mf < MF; mf++)
#pragma unroll
        for (int nf = 0; nf < NF; nf++)
          acc[mf][nf] = __builtin_amdgcn_mfma_f32_16x16x32_bf16(a[mf], bl[nf], acc[mf][nf], 0, 0, 0);
    }
  }

  // ---- epilogue: LIF state update (+ z into LDS for pooling) ----
  if constexpr (POOLZ) __syncthreads();   // smem (A) dead; reuse as z buffer
  unsigned short* zb = (unsigned short*)smem;
  int mbase = (b*HIM + y0)*WI;
#pragma unroll
  for (int mf = 0; mf < MF; mf++)
#pragma unroll
    for (int nf = 0; nf < NF; nf++) {
      int chn = wn*NF*16 + nf*16 + (lane & 15);
      int chg = nt*BN + chn;
#pragma unroll
      for (int r = 0; r < 4; r++) {
        int pix = wm*MF*16 + mf*16 + (lane>>4)*4 + r;
        long idx = (long)(mbase + pix)*COUT + chg;
        float cv = acc[mf][nf][r];
        if constexpr (KSPLIT) {
          atomicAdd(partial + idx, cv);
        } else {
          float vv = 0.f, ii = 0.f;
          if (t != 0) { vv = vst[idx]; ii = ist[idx]; }
          float vdec = vv + DTM*((0.0f - vv) + ii);
          bool z = (vdec - VTH) > 0.0f;
          vst[idx] = z ? 0.0f : vdec;
          ist[idx] = SYN*ii + cv;
          if constexpr (POOLZ) zb[pix*BN + chn] = z ? 0x3F80 : 0;
        }
      }
    }

  // ---- fused 2x2 max-pool of spikes (binary max == OR), coalesced write ----
  if constexpr (POOLZ) {
    __syncthreads();
    constexpr int WP = WI/2, PR = ROWS/2, CH16 = BN/8;
    for (int c = tid; c < PR*WP*CH16; c += THREADS) {
      int ppx = c / CH16, ck = c % CH16;
      int py = ppx / WP, px = ppx % WP;
      int b0 = ((2*py)*WI + 2*px)*BN + ck*8;
      u32x4 q0 = *(const u32x4*)(zb + b0);
      u32x4 q1 = *(const u32x4*)(zb + b0 + BN);
      u32x4 q2 = *(const u32x4*)(zb + b0 + WI*BN);
      u32x4 q3 = *(const u32x4*)(zb + b0 + WI*BN + BN);
      u32x4 vo = (q0|q1)|(q2|q3);
      long g = ((long)(b*(HIM/2) + (y0>>1) + py)*WP + px)*COUT + nt*BN + ck*8;
      *(u32x4*)(zpool + g) = vo;
    }
  }
}

// ---------------------------------------------------------------------------
// K5: LIF4 (from conv4 partial) + 2x2 pool + FC(4096->10) + LI + noise + max.
// ---------------------------------------------------------------------------
__global__ __launch_bounds__(256) void k5_lif4_fc(
    float* __restrict__ partial, float* __restrict__ v4, float* __restrict__ i4,
    const float* __restrict__ wfc, const float* __restrict__ noise,
    float* __restrict__ vl, float* __restrict__ il, float* __restrict__ dout, int t)
{
  __shared__ unsigned long long zbits[64][4];
  __shared__ unsigned long long pb[64];
  __shared__ float red[4][10];
  int tid = threadIdx.x, b = blockIdx.x;
  int px = tid >> 2, cq = tid & 3;
  long base = ((long)b*64 + px)*256 + cq*64;
  unsigned long long mask = 0ull;
#pragma unroll
  for (int q = 0; q < 16; q++) {
    float4 pv = *(const float4*)(partial + base + q*4);
    float vv[4] = {0.f,0.f,0.f,0.f}, ii[4] = {0.f,0.f,0.f,0.f};
    if (t != 0) {
      float4 v4v = *(const float4*)(v4 + base + q*4);
      float4 i4v = *(const float4*)(i4 + base + q*4);
      vv[0]=v4v.x; vv[1]=v4v.y; vv[2]=v4v.z; vv[3]=v4v.w;
      ii[0]=i4v.x; ii[1]=i4v.y; ii[2]=i4v.z; ii[3]=i4v.w;
    }
    float cv[4] = {pv.x, pv.y, pv.z, pv.w};
#pragma unroll
    for (int s = 0; s < 4; s++) {
      float vdec = vv[s] + DTM*((0.0f - vv[s]) + ii[s]);
      bool z = (vdec - VTH) > 0.0f;
      vv[s] = z ? 0.0f : vdec;
      ii[s] = SYN*ii[s] + cv[s];
      if (z) mask |= (1ull << (q*4 + s));
    }
    *(float4*)(v4 + base + q*4) = make_float4(vv[0],vv[1],vv[2],vv[3]);
    *(float4*)(i4 + base + q*4) = make_float4(ii[0],ii[1],ii[2],ii[3]);
    *(float4*)(partial + base + q*4) = make_float4(0.f,0.f,0.f,0.f);
  }
  zbits[px][cq] = mask;
  __syncthreads();
  if (tid < 64) {
    int py = tid >> 4, rm = tid & 15, pxx = rm >> 2, c4 = rm & 3;
    int p00 = (2*py)*8 + 2*pxx;
    pb[tid] = zbits[p00][c4] | zbits[p00+1][c4] | zbits[p00+8][c4] | zbits[p00+9][c4];
  }
  __syncthreads();
  float sums[10];
#pragma unroll
  for (int j = 0; j < 10; j++) sums[j] = 0.f;
  for (int q = 0; q < 16; q++) {
    int k = q*256 + tid;
    int c = k >> 4, s = k & 15, yy = s >> 2, xx = s & 3;
    unsigned long long bits = pb[yy*16 + xx*4 + (c >> 6)];
    if ((bits >> (c & 63)) & 1ull) {
#pragma unroll
      for (int j = 0; j < 10; j++) sums[j] += wfc[j*4096 + k];
    }
  }
#pragma unroll
  for (int j = 0; j < 10; j++) {
    float v = sums[j];
    for (int off = 32; off; off >>= 1) v += __shfl_xor(v, off);
    if ((tid & 63) == 0) red[tid>>6][j] = v;
  }
  __syncthreads();
  if (tid < 10) {
    float o = red[0][tid] + red[1][tid] + red[2][tid] + red[3][tid];
    float vo = 0.f, io = 0.f;
    if (t != 0) { vo = vl[b*10 + tid]; io = il[b*10 + tid]; }
    float vn = vo + DTM*((0.0f - vo) + io);
    float inw = SYN*io + o;
    vl[b*10 + tid] = vn; il[b*10 + tid] = inw;
    float volt = vn + 0.001f*noise[((long)t*32 + b)*10 + tid];
    dout[b*10 + tid] = (t == 0) ? volt : fmaxf(dout[b*10 + tid], volt);
  }
}

// ---------------------------------------------------------------------------
extern "C" void kernel_launch(void* const* d_in, const int* in_sizes, int n_in,
                              void* d_out, int out_size, void* d_ws, size_t ws_size,
                              hipStream_t stream)
{
  const float* x     = (const float*)d_in[0];
  const float* noise = (const float*)d_in[1];
  const float* w1    = (const float*)d_in[2];
  const float* w2    = (const float*)d_in[3];
  const float* w3    = (const float*)d_in[4];
  const float* w4    = (const float*)d_in[5];
  const float* wfc   = (const float*)d_in[6];
  float* dout = (float*)d_out;

  char* ws = (char*)d_ws;
  size_t off = 0;
  auto alloc = [&](size_t bytes) -> char* {
    char* p = ws + off;
    off = (off + bytes + 255) & ~(size_t)255;
    return p;
  };
  float* v1 = (float*)alloc(2097152u*4); float* i1 = (float*)alloc(2097152u*4);
  float* v2 = (float*)alloc(4194304u*4); float* i2 = (float*)alloc(4194304u*4);
  float* v3 = (float*)alloc(2097152u*4); float* i3 = (float*)alloc(2097152u*4);
  float* v4 = (float*)alloc(524288u*4);  float* i4 = (float*)alloc(524288u*4);
  unsigned short* z1  = (unsigned short*)alloc(2097152u*2);   // full-res spikes L1
  unsigned short* z2p = (unsigned short*)alloc(1048576u*2);   // pooled spikes L2: [32][16][16][128]
  unsigned short* z3p = (unsigned short*)alloc(524288u*2);    // pooled spikes L3: [32][8][8][256]
  float* partial = (float*)alloc(524288u*4);
  float* vl = (float*)alloc(1280);
  float* il = (float*)alloc(1280);
  unsigned short* wb2h = (unsigned short*)alloc(73728u*2);
  unsigned short* wb2m = (unsigned short*)alloc(73728u*2);
  unsigned short* wb2l = (unsigned short*)alloc(73728u*2);
  unsigned short* wb3h = (unsigned short*)alloc(294912u*2);
  unsigned short* wb3m = (unsigned short*)alloc(294912u*2);
  unsigned short* wb3l = (unsigned short*)alloc(294912u*2);
  unsigned short* wb4h = (unsigned short*)alloc(589824u*2);
  unsigned short* wb4m = (unsigned short*)alloc(589824u*2);
  unsigned short* wb4l = (unsigned short*)alloc(589824u*2);

  prep_kernel<<<5792, 256, 0, stream>>>(w2, w3, w4,
      wb2h, wb2m, wb2l, wb3h, wb3m, wb3l, wb4h, wb4m, wb4l, partial);

  for (int t = 0; t < 16; t++) {
    k1_conv1_lif<<<512, 256, 0, stream>>>(x, w1, v1, i1, z1, t);
    // conv2: 64->128 @32x32 full-res in, pooled-z out. BM=128,BN=128, 512thr, grid 256
    conv_lif<4,2,2,4, 64,32,32,128, 64,1,false,true><<<256, 512, 0, stream>>>(
        z1, wb2h, wb2m, wb2l, v2, i2, z2p, nullptr, t);
    // conv3: 128->256 @16x16 pooled in, pooled-z out. BM=64,BN=64, NT=4, grid 512
    conv_lif<4,1,1,4,128,16,16,256,128,4,false,true><<<512, 256, 0, stream>>>(
        z2p, wb3h, wb3m, wb3l, v3, i3, z3p, nullptr, t);
    // conv4: 256->256 @8x8 pooled in, KSPLIT=2 atomic partial. BM=32,BN=64, NT=4, grid 512
    conv_lif<2,1,1,4,128, 8, 8,256,256,4,true,false><<<512, 256, 0, stream>>>(
        z3p, wb4h, wb4m, wb4l, nullptr, nullptr, nullptr, partial, t);
    k5_lif4_fc<<<32, 256, 0, stream>>>(partial, v4, i4, wfc, noise, vl, il, dout, t);
  }
}

// Round 5
// 2355.468 us; speedup vs baseline: 1.0012x; 1.0012x over previous
//
#include <hip/hip_runtime.h>

typedef __attribute__((ext_vector_type(8))) short short8;
typedef __attribute__((ext_vector_type(4))) float f32x4;
typedef __attribute__((ext_vector_type(4))) unsigned int u32x4;

#define DEV static __device__ __forceinline__

DEV unsigned short f2bf(float f){
  unsigned int u = __float_as_uint(f);
  u += 0x7FFFu + ((u >> 16) & 1u);
  return (unsigned short)(u >> 16);
}
DEV float bf2f(unsigned short h){ return __uint_as_float(((unsigned int)h) << 16); }

#define DTM 0.1f   /* DT*TAU_MEM_INV */
#define SYN 0.8f   /* 1 - DT*TAU_SYN_INV */
#define VTH 0.2f

// ---------------------------------------------------------------------------
// prep: build [tap][co][ci] bf16 hi/mid/lo weight digits, zero conv4 partial.
// ---------------------------------------------------------------------------
__global__ __launch_bounds__(256) void prep_kernel(
    const float* __restrict__ w2, const float* __restrict__ w3, const float* __restrict__ w4,
    unsigned short* __restrict__ wb2h, unsigned short* __restrict__ wb2m, unsigned short* __restrict__ wb2l,
    unsigned short* __restrict__ wb3h, unsigned short* __restrict__ wb3m, unsigned short* __restrict__ wb3l,
    unsigned short* __restrict__ wb4h, unsigned short* __restrict__ wb4m, unsigned short* __restrict__ wb4l,
    float* __restrict__ partial)
{
  const int N2 = 9*128*64, N3 = 9*256*128, N4 = 9*256*256, NP = 2048*256;
  int tid = blockIdx.x*256 + threadIdx.x;
  if (tid < N2) {
    int tap = tid/(128*64), r = tid%(128*64), co = r>>6, ci = r&63;
    float w = w2[(co*64+ci)*9 + tap];
    unsigned short h = f2bf(w);       float r1 = w - bf2f(h);
    unsigned short m = f2bf(r1);      float r2 = r1 - bf2f(m);
    wb2h[tid] = h; wb2m[tid] = m; wb2l[tid] = f2bf(r2);
    return;
  }
  tid -= N2;
  if (tid < N3) {
    int tap = tid/(256*128), r = tid%(256*128), co = r>>7, ci = r&127;
    float w = w3[(co*128+ci)*9 + tap];
    unsigned short h = f2bf(w);       float r1 = w - bf2f(h);
    unsigned short m = f2bf(r1);      float r2 = r1 - bf2f(m);
    wb3h[tid] = h; wb3m[tid] = m; wb3l[tid] = f2bf(r2);
    return;
  }
  tid -= N3;
  if (tid < N4) {
    int tap = tid/(256*256), r = tid%(256*256), co = r>>8, ci = r&255;
    float w = w4[(co*256+ci)*9 + tap];
    unsigned short h = f2bf(w);       float r1 = w - bf2f(h);
    unsigned short m = f2bf(r1);      float r2 = r1 - bf2f(m);
    wb4h[tid] = h; wb4m[tid] = m; wb4l[tid] = f2bf(r2);
    return;
  }
  tid -= N4;
  if (tid < NP) partial[tid] = 0.f;
}

// ---------------------------------------------------------------------------
// K1: conv1 (fp32 direct, 3->64, 3x3 SAME) + LIF1. grid 512 = 32 imgs x 16 row-pairs
// ---------------------------------------------------------------------------
__global__ __launch_bounds__(256) void k1_conv1_lif(
    const float* __restrict__ x, const float* __restrict__ w1,
    float* __restrict__ v1, float* __restrict__ i1,
    unsigned short* __restrict__ z1, int t)
{
  __shared__ float xs[3][4][34];
  __shared__ float wl[27][64];
  int tid = threadIdx.x;
  int b = blockIdx.x >> 4, y0 = (blockIdx.x & 15) * 2;
  for (int e = tid; e < 3*4*34; e += 256) {
    int ci = e/136, r2 = e%136, r = r2/34, xi = r2%34;
    int y = y0 - 1 + r, xg = xi - 1;
    float v = 0.f;
    if (y >= 0 && y < 32 && xg >= 0 && xg < 32)
      v = x[((t*32 + b)*3 + ci)*1024 + y*32 + xg];
    xs[ci][r][xi] = v;
  }
  for (int e = tid; e < 27*64; e += 256) {
    int row = e >> 6, co = e & 63;
    int ci = row % 3, tap = row / 3, ky = tap/3, kx = tap%3;
    wl[row][co] = w1[((co*3+ci)*3+ky)*3+kx];
  }
  __syncthreads();
  int px = tid >> 2, cg = tid & 3;
  int ly = px >> 5, lx = px & 31;
  float acc[16];
#pragma unroll
  for (int q = 0; q < 16; q++) acc[q] = 0.f;
#pragma unroll
  for (int ky = 0; ky < 3; ky++)
#pragma unroll
    for (int kx = 0; kx < 3; kx++)
#pragma unroll
      for (int ci = 0; ci < 3; ci++) {
        float xv = xs[ci][ly+ky][lx+kx];
        const float4* wr = (const float4*)&wl[(ky*3+kx)*3+ci][cg*16];
#pragma unroll
        for (int q = 0; q < 4; q++) {
          float4 w4 = wr[q];
          acc[q*4+0] = fmaf(xv, w4.x, acc[q*4+0]);
          acc[q*4+1] = fmaf(xv, w4.y, acc[q*4+1]);
          acc[q*4+2] = fmaf(xv, w4.z, acc[q*4+2]);
          acc[q*4+3] = fmaf(xv, w4.w, acc[q*4+3]);
        }
      }
  int m_g = b*1024 + (y0+ly)*32 + lx;
  unsigned short zb[16];
#pragma unroll
  for (int q = 0; q < 4; q++) {
    int idx = m_g*64 + cg*16 + q*4;
    float vv[4] = {0.f,0.f,0.f,0.f}, ii[4] = {0.f,0.f,0.f,0.f};
    if (t != 0) {
      float4 v4 = *(const float4*)(v1+idx); float4 i4 = *(const float4*)(i1+idx);
      vv[0]=v4.x; vv[1]=v4.y; vv[2]=v4.z; vv[3]=v4.w;
      ii[0]=i4.x; ii[1]=i4.y; ii[2]=i4.z; ii[3]=i4.w;
    }
#pragma unroll
    for (int s = 0; s < 4; s++) {
      float vdec = vv[s] + DTM*((0.0f - vv[s]) + ii[s]);
      bool z = (vdec - VTH) > 0.0f;
      vv[s] = z ? 0.0f : vdec;
      ii[s] = SYN*ii[s] + acc[q*4+s];
      zb[q*4+s] = z ? 0x3F80 : 0;
    }
    *(float4*)(v1+idx) = make_float4(vv[0],vv[1],vv[2],vv[3]);
    *(float4*)(i1+idx) = make_float4(ii[0],ii[1],ii[2],ii[3]);
  }
  u32x4 za, zc;
  za[0]=zb[0]|((unsigned)zb[1]<<16); za[1]=zb[2]|((unsigned)zb[3]<<16);
  za[2]=zb[4]|((unsigned)zb[5]<<16); za[3]=zb[6]|((unsigned)zb[7]<<16);
  zc[0]=zb[8]|((unsigned)zb[9]<<16); zc[1]=zb[10]|((unsigned)zb[11]<<16);
  zc[2]=zb[12]|((unsigned)zb[13]<<16); zc[3]=zb[14]|((unsigned)zb[15]<<16);
  *(u32x4*)(z1 + m_g*64 + cg*16) = za;
  *(u32x4*)(z1 + m_g*64 + cg*16 + 8) = zc;
}

// ---------------------------------------------------------------------------
// Implicit-GEMM conv (3x3 SAME) over binary spikes, bf16 hi/mid/lo 3-digit
// MFMA. A staged once in LDS (XOR-swizzled); B fragments loaded per-lane
// DIRECTLY from global (L2) -- K-loop is barrier-free.
// Epilogue: fused LIF + (POOLZ) 2x2 max-pool of spikes via LDS OR-reduce,
// or (KSPLIT) atomic partial accumulation (exactly 2 adds/elem: deterministic).
// ---------------------------------------------------------------------------
template<int MF, int NF, int WM, int WN, int CIN_A, int WI, int HIM,
         int COUT, int CIN_SRC, int NT, bool KSPLIT, bool POOLZ>
__global__ __launch_bounds__(WM*WN*64, 1) void conv_lif(
    const unsigned short* __restrict__ zsrc,
    const unsigned short* __restrict__ wbh, const unsigned short* __restrict__ wbm,
    const unsigned short* __restrict__ wbl,
    float* __restrict__ vst, float* __restrict__ ist,
    unsigned short* __restrict__ zpool, float* __restrict__ partial, int t)
{
  constexpr int THREADS = WM*WN*64;
  constexpr int BM = WM*MF*16;
  constexpr int BN = WN*NF*16;
  constexpr int ROWS = BM/WI;
  constexpr int SLOTW = WI+2;
  constexpr int SLOTS = (ROWS+2)*SLOTW;
  constexpr int CPH = CIN_A/64;
  constexpr int P = 9*CPH;
  constexpr int MT_PER_B = (HIM*WI)/BM;
  constexpr int ACH = CIN_A/8;
  constexpr int ACHUNKS = SLOTS*ACH;
  constexpr int LDS_A = SLOTS*CIN_A*2;
  constexpr int LDS_Z = POOLZ ? BM*BN*2 : 16;
  constexpr int LDS_SZ = LDS_A > LDS_Z ? LDS_A : LDS_Z;
  static_assert(LDS_SZ <= 48*1024, "LDS");

  __shared__ __align__(16) char smem[LDS_SZ];

  int tid = threadIdx.x;
  int rem = blockIdx.x;
  int kh = 0;
  if constexpr (KSPLIT) { kh = rem & 1; rem >>= 1; }
  int nt = 0;
  if constexpr (NT > 1) { nt = rem % NT; rem /= NT; }
  int b = rem / MT_PER_B;
  int y0 = (rem % MT_PER_B) * ROWS;
  int lane = tid & 63;
  int wv = tid >> 6, wn = wv % WN, wm = wv / WN;
  int klane = (lane >> 4) * 8;
  int csrc0 = KSPLIT ? kh*128 : 0;

  // ---- stage A tile (once; t-invariant addresses) ----
  for (int ch = tid; ch < ACHUNKS; ch += THREADS) {
    int slot = ch / ACH, g = ch % ACH;
    int yr = slot / SLOTW, xr = slot % SLOTW;
    int y = y0 + yr - 1, xg = xr - 1;
    u32x4 val; val[0]=0; val[1]=0; val[2]=0; val[3]=0;
    if (y >= 0 && y < HIM && xg >= 0 && xg < WI)
      val = *(const u32x4*)(zsrc + ((long)(b*HIM + y)*WI + xg)*CIN_SRC + csrc0 + g*8);
    int addr = ((slot*CIN_A + g*8)*2) ^ ((slot & 7) << 4);
    *(u32x4*)(smem + addr) = val;
  }

  f32x4 acc[MF][NF];
#pragma unroll
  for (int mf = 0; mf < MF; mf++)
#pragma unroll
    for (int nf = 0; nf < NF; nf++) {
      acc[mf][nf][0]=0.f; acc[mf][nf][1]=0.f; acc[mf][nf][2]=0.f; acc[mf][nf][3]=0.f;
    }

  int grow0 = nt*BN + wn*NF*16 + (lane & 15);
  __syncthreads();

  // ---- barrier-free K loop ----
#pragma unroll 2
  for (int p = 0; p < P; p++) {
    int tap = p / CPH, cs = p % CPH;
    int dy = tap/3 - 1, dx = tap%3 - 1;
#pragma unroll
    for (int ks = 0; ks < 2; ks++) {
      short8 bh[NF], bm_[NF], bl[NF];
#pragma unroll
      for (int nf = 0; nf < NF; nf++) {
        long bo = ((long)tap*COUT + grow0 + nf*16)*CIN_SRC + csrc0 + cs*64 + ks*32 + klane;
        bh[nf]  = *(const short8*)(wbh + bo);
        bm_[nf] = *(const short8*)(wbm + bo);
        bl[nf]  = *(const short8*)(wbl + bo);
      }
      short8 a[MF];
#pragma unroll
      for (int mf = 0; mf < MF; mf++) {
        int pl = wm*MF*16 + mf*16 + (lane & 15);
        int yl = pl / WI, xl = pl % WI;
        int slot = (yl + dy + 1)*SLOTW + (xl + dx + 1);
        int addr = ((slot*CIN_A + cs*64 + ks*32 + klane)*2) ^ ((slot & 7) << 4);
        a[mf] = *(const short8*)(smem + addr);
      }
#pragma unroll
      for (int mf = 0; mf < MF; mf++)
#pragma unroll
        for (int nf = 0; nf < NF; nf++)
          acc[mf][nf] = __builtin_amdgcn_mfma_f32_16x16x32_bf16(a[mf], bh[nf], acc[mf][nf], 0, 0, 0);
#pragma unroll
      for (int mf = 0; mf < MF; mf++)
#pragma unroll
        for (int nf = 0; nf < NF; nf++)
          acc[mf][nf] = __builtin_amdgcn_mfma_f32_16x16x32_bf16(a[mf], bm_[nf], acc[mf][nf], 0, 0, 0);
#pragma unroll
      for (int mf = 0; mf < MF; mf++)
#pragma unroll
        for (int nf = 0; nf < NF; nf++)
          acc[mf][nf] = __builtin_amdgcn_mfma_f32_16x16x32_bf16(a[mf], bl[nf], acc[mf][nf], 0, 0, 0);
    }
  }

  // ---- epilogue: LIF state update (+ z into LDS for pooling) ----
  if constexpr (POOLZ) __syncthreads();   // smem (A) dead; reuse as z buffer
  unsigned short* zb = (unsigned short*)smem;
  int mbase = (b*HIM + y0)*WI;
#pragma unroll
  for (int mf = 0; mf < MF; mf++)
#pragma unroll
    for (int nf = 0; nf < NF; nf++) {
      int chn = wn*NF*16 + nf*16 + (lane & 15);
      int chg = nt*BN + chn;
#pragma unroll
      for (int r = 0; r < 4; r++) {
        int pix = wm*MF*16 + mf*16 + (lane>>4)*4 + r;
        long idx = (long)(mbase + pix)*COUT + chg;
        float cv = acc[mf][nf][r];
        if constexpr (KSPLIT) {
          atomicAdd(partial + idx, cv);
        } else {
          float vv = 0.f, ii = 0.f;
          if (t != 0) { vv = vst[idx]; ii = ist[idx]; }
          float vdec = vv + DTM*((0.0f - vv) + ii);
          bool z = (vdec - VTH) > 0.0f;
          vst[idx] = z ? 0.0f : vdec;
          ist[idx] = SYN*ii + cv;
          if constexpr (POOLZ) zb[pix*BN + chn] = z ? 0x3F80 : 0;
        }
      }
    }

  // ---- fused 2x2 max-pool of spikes (binary max == OR), coalesced write ----
  if constexpr (POOLZ) {
    __syncthreads();
    constexpr int WP = WI/2, PR = ROWS/2, CH16 = BN/8;
    for (int c = tid; c < PR*WP*CH16; c += THREADS) {
      int ppx = c / CH16, ck = c % CH16;
      int py = ppx / WP, px = ppx % WP;
      int b0 = ((2*py)*WI + 2*px)*BN + ck*8;
      u32x4 q0 = *(const u32x4*)(zb + b0);
      u32x4 q1 = *(const u32x4*)(zb + b0 + BN);
      u32x4 q2 = *(const u32x4*)(zb + b0 + WI*BN);
      u32x4 q3 = *(const u32x4*)(zb + b0 + WI*BN + BN);
      u32x4 vo = (q0|q1)|(q2|q3);
      long g = ((long)(b*(HIM/2) + (y0>>1) + py)*WP + px)*COUT + nt*BN + ck*8;
      *(u32x4*)(zpool + g) = vo;
    }
  }
}

// ---------------------------------------------------------------------------
// K5: LIF4 (from conv4 partial) + 2x2 pool + FC(4096->10) + LI + noise + max.
// ---------------------------------------------------------------------------
__global__ __launch_bounds__(256) void k5_lif4_fc(
    float* __restrict__ partial, float* __restrict__ v4, float* __restrict__ i4,
    const float* __restrict__ wfc, const float* __restrict__ noise,
    float* __restrict__ vl, float* __restrict__ il, float* __restrict__ dout, int t)
{
  __shared__ unsigned long long zbits[64][4];
  __shared__ unsigned long long pb[64];
  __shared__ float red[4][10];
  int tid = threadIdx.x, b = blockIdx.x;
  int px = tid >> 2, cq = tid & 3;
  long base = ((long)b*64 + px)*256 + cq*64;
  unsigned long long mask = 0ull;
#pragma unroll
  for (int q = 0; q < 16; q++) {
    float4 pv = *(const float4*)(partial + base + q*4);
    float vv[4] = {0.f,0.f,0.f,0.f}, ii[4] = {0.f,0.f,0.f,0.f};
    if (t != 0) {
      float4 v4v = *(const float4*)(v4 + base + q*4);
      float4 i4v = *(const float4*)(i4 + base + q*4);
      vv[0]=v4v.x; vv[1]=v4v.y; vv[2]=v4v.z; vv[3]=v4v.w;
      ii[0]=i4v.x; ii[1]=i4v.y; ii[2]=i4v.z; ii[3]=i4v.w;
    }
    float cv[4] = {pv.x, pv.y, pv.z, pv.w};
#pragma unroll
    for (int s = 0; s < 4; s++) {
      float vdec = vv[s] + DTM*((0.0f - vv[s]) + ii[s]);
      bool z = (vdec - VTH) > 0.0f;
      vv[s] = z ? 0.0f : vdec;
      ii[s] = SYN*ii[s] + cv[s];
      if (z) mask |= (1ull << (q*4 + s));
    }
    *(float4*)(v4 + base + q*4) = make_float4(vv[0],vv[1],vv[2],vv[3]);
    *(float4*)(i4 + base + q*4) = make_float4(ii[0],ii[1],ii[2],ii[3]);
    *(float4*)(partial + base + q*4) = make_float4(0.f,0.f,0.f,0.f);
  }
  zbits[px][cq] = mask;
  __syncthreads();
  if (tid < 64) {
    int py = tid >> 4, rm = tid & 15, pxx = rm >> 2, c4 = rm & 3;
    int p00 = (2*py)*8 + 2*pxx;
    pb[tid] = zbits[p00][c4] | zbits[p00+1][c4] | zbits[p00+8][c4] | zbits[p00+9][c4];
  }
  __syncthreads();
  float sums[10];
#pragma unroll
  for (int j = 0; j < 10; j++) sums[j] = 0.f;
  for (int q = 0; q < 16; q++) {
    int k = q*256 + tid;
    int c = k >> 4, s = k & 15, yy = s >> 2, xx = s & 3;
    unsigned long long bits = pb[yy*16 + xx*4 + (c >> 6)];
    if ((bits >> (c & 63)) & 1ull) {
#pragma unroll
      for (int j = 0; j < 10; j++) sums[j] += wfc[j*4096 + k];
    }
  }
#pragma unroll
  for (int j = 0; j < 10; j++) {
    float v = sums[j];
    for (int off = 32; off; off >>= 1) v += __shfl_xor(v, off);
    if ((tid & 63) == 0) red[tid>>6][j] = v;
  }
  __syncthreads();
  if (tid < 10) {
    float o = red[0][tid] + red[1][tid] + red[2][tid] + red[3][tid];
    float vo = 0.f, io = 0.f;
    if (t != 0) { vo = vl[b*10 + tid]; io = il[b*10 + tid]; }
    float vn = vo + DTM*((0.0f - vo) + io);
    float inw = SYN*io + o;
    vl[b*10 + tid] = vn; il[b*10 + tid] = inw;
    float volt = vn + 0.001f*noise[((long)t*32 + b)*10 + tid];
    dout[b*10 + tid] = (t == 0) ? volt : fmaxf(dout[b*10 + tid], volt);
  }
}

// ---------------------------------------------------------------------------
extern "C" void kernel_launch(void* const* d_in, const int* in_sizes, int n_in,
                              void* d_out, int out_size, void* d_ws, size_t ws_size,
                              hipStream_t stream)
{
  const float* x     = (const float*)d_in[0];
  const float* noise = (const float*)d_in[1];
  const float* w1    = (const float*)d_in[2];
  const float* w2    = (const float*)d_in[3];
  const float* w3    = (const float*)d_in[4];
  const float* w4    = (const float*)d_in[5];
  const float* wfc   = (const float*)d_in[6];
  float* dout = (float*)d_out;

  char* ws = (char*)d_ws;
  size_t off = 0;
  auto alloc = [&](size_t bytes) -> char* {
    char* p = ws + off;
    off = (off + bytes + 255) & ~(size_t)255;
    return p;
  };
  float* v1 = (float*)alloc(2097152u*4); float* i1 = (float*)alloc(2097152u*4);
  float* v2 = (float*)alloc(4194304u*4); float* i2 = (float*)alloc(4194304u*4);
  float* v3 = (float*)alloc(2097152u*4); float* i3 = (float*)alloc(2097152u*4);
  float* v4 = (float*)alloc(524288u*4);  float* i4 = (float*)alloc(524288u*4);
  unsigned short* z1  = (unsigned short*)alloc(2097152u*2);   // full-res spikes L1
  unsigned short* z2p = (unsigned short*)alloc(1048576u*2);   // pooled spikes L2: [32][16][16][128]
  unsigned short* z3p = (unsigned short*)alloc(524288u*2);    // pooled spikes L3: [32][8][8][256]
  float* partial = (float*)alloc(524288u*4);
  float* vl = (float*)alloc(1280);
  float* il = (float*)alloc(1280);
  unsigned short* wb2h = (unsigned short*)alloc(73728u*2);
  unsigned short* wb2m = (unsigned short*)alloc(73728u*2);
  unsigned short* wb2l = (unsigned short*)alloc(73728u*2);
  unsigned short* wb3h = (unsigned short*)alloc(294912u*2);
  unsigned short* wb3m = (unsigned short*)alloc(294912u*2);
  unsigned short* wb3l = (unsigned short*)alloc(294912u*2);
  unsigned short* wb4h = (unsigned short*)alloc(589824u*2);
  unsigned short* wb4m = (unsigned short*)alloc(589824u*2);
  unsigned short* wb4l = (unsigned short*)alloc(589824u*2);

  prep_kernel<<<5792, 256, 0, stream>>>(w2, w3, w4,
      wb2h, wb2m, wb2l, wb3h, wb3m, wb3l, wb4h, wb4m, wb4l, partial);

  for (int t = 0; t < 16; t++) {
    k1_conv1_lif<<<512, 256, 0, stream>>>(x, w1, v1, i1, z1, t);
    // conv2: 64->128 @32x32 full-res in, pooled-z out. BM=128,BN=128, 512thr, grid 256
    conv_lif<4,2,2,4, 64,32,32,128, 64,1,false,true><<<256, 512, 0, stream>>>(
        z1, wb2h, wb2m, wb2l, v2, i2, z2p, nullptr, t);
    // conv3: 128->256 @16x16 pooled in, pooled-z out. BM=64,BN=64, NT=4, grid 512
    conv_lif<4,1,1,4,128,16,16,256,128,4,false,true><<<512, 256, 0, stream>>>(
        z2p, wb3h, wb3m, wb3l, v3, i3, z3p, nullptr, t);
    // conv4: 256->256 @8x8 pooled in, KSPLIT=2 atomic partial. BM=32,BN=64, NT=4, grid 512
    conv_lif<2,1,1,4,128, 8, 8,256,256,4,true,false><<<512, 256, 0, stream>>>(
        z3p, wb4h, wb4m, wb4l, nullptr, nullptr, nullptr, partial, t);
    k5_lif4_fc<<<32, 256, 0, stream>>>(partial, v4, i4, wfc, noise, vl, il, dout, t);
  }
}

// Round 6
// 2354.784 us; speedup vs baseline: 1.0015x; 1.0003x over previous
//
#include <hip/hip_runtime.h>

typedef __attribute__((ext_vector_type(8))) short short8;
typedef __attribute__((ext_vector_type(4))) float f32x4;
typedef __attribute__((ext_vector_type(4))) unsigned int u32x4;

#define DEV static __device__ __forceinline__

DEV unsigned short f2bf(float f){
  unsigned int u = __float_as_uint(f);
  u += 0x7FFFu + ((u >> 16) & 1u);
  return (unsigned short)(u >> 16);
}
DEV float bf2f(unsigned short h){ return __uint_as_float(((unsigned int)h) << 16); }

#define DTM 0.1f   /* DT*TAU_MEM_INV */
#define SYN 0.8f   /* 1 - DT*TAU_SYN_INV */
#define VTH 0.2f

// ---------------------------------------------------------------------------
// prep: build [tap][co][ci] bf16 hi/mid/lo weight digits, zero conv4 partial.
// ---------------------------------------------------------------------------
__global__ __launch_bounds__(256) void prep_kernel(
    const float* __restrict__ w2, const float* __restrict__ w3, const float* __restrict__ w4,
    unsigned short* __restrict__ wb2h, unsigned short* __restrict__ wb2m, unsigned short* __restrict__ wb2l,
    unsigned short* __restrict__ wb3h, unsigned short* __restrict__ wb3m, unsigned short* __restrict__ wb3l,
    unsigned short* __restrict__ wb4h, unsigned short* __restrict__ wb4m, unsigned short* __restrict__ wb4l,
    float* __restrict__ partial)
{
  const int N2 = 9*128*64, N3 = 9*256*128, N4 = 9*256*256, NP = 2048*256;
  int tid = blockIdx.x*256 + threadIdx.x;
  if (tid < N2) {
    int tap = tid/(128*64), r = tid%(128*64), co = r>>6, ci = r&63;
    float w = w2[(co*64+ci)*9 + tap];
    unsigned short h = f2bf(w);       float r1 = w - bf2f(h);
    unsigned short m = f2bf(r1);      float r2 = r1 - bf2f(m);
    wb2h[tid] = h; wb2m[tid] = m; wb2l[tid] = f2bf(r2);
    return;
  }
  tid -= N2;
  if (tid < N3) {
    int tap = tid/(256*128), r = tid%(256*128), co = r>>7, ci = r&127;
    float w = w3[(co*128+ci)*9 + tap];
    unsigned short h = f2bf(w);       float r1 = w - bf2f(h);
    unsigned short m = f2bf(r1);      float r2 = r1 - bf2f(m);
    wb3h[tid] = h; wb3m[tid] = m; wb3l[tid] = f2bf(r2);
    return;
  }
  tid -= N3;
  if (tid < N4) {
    int tap = tid/(256*256), r = tid%(256*256), co = r>>8, ci = r&255;
    float w = w4[(co*256+ci)*9 + tap];
    unsigned short h = f2bf(w);       float r1 = w - bf2f(h);
    unsigned short m = f2bf(r1);      float r2 = r1 - bf2f(m);
    wb4h[tid] = h; wb4m[tid] = m; wb4l[tid] = f2bf(r2);
    return;
  }
  tid -= N4;
  if (tid < NP) partial[tid] = 0.f;
}

// ---------------------------------------------------------------------------
// K1: conv1 (fp32 direct, 3->64, 3x3 SAME) + LIF1. grid 512 = 32 imgs x 16 row-pairs
// ---------------------------------------------------------------------------
__global__ __launch_bounds__(256) void k1_conv1_lif(
    const float* __restrict__ x, const float* __restrict__ w1,
    float* __restrict__ v1, float* __restrict__ i1,
    unsigned short* __restrict__ z1, int t)
{
  __shared__ float xs[3][4][34];
  __shared__ float wl[27][64];
  int tid = threadIdx.x;
  int b = blockIdx.x >> 4, y0 = (blockIdx.x & 15) * 2;
  for (int e = tid; e < 3*4*34; e += 256) {
    int ci = e/136, r2 = e%136, r = r2/34, xi = r2%34;
    int y = y0 - 1 + r, xg = xi - 1;
    float v = 0.f;
    if (y >= 0 && y < 32 && xg >= 0 && xg < 32)
      v = x[((t*32 + b)*3 + ci)*1024 + y*32 + xg];
    xs[ci][r][xi] = v;
  }
  for (int e = tid; e < 27*64; e += 256) {
    int row = e >> 6, co = e & 63;
    int ci = row % 3, tap = row / 3, ky = tap/3, kx = tap%3;
    wl[row][co] = w1[((co*3+ci)*3+ky)*3+kx];
  }
  __syncthreads();
  int px = tid >> 2, cg = tid & 3;
  int ly = px >> 5, lx = px & 31;
  float acc[16];
#pragma unroll
  for (int q = 0; q < 16; q++) acc[q] = 0.f;
#pragma unroll
  for (int ky = 0; ky < 3; ky++)
#pragma unroll
    for (int kx = 0; kx < 3; kx++)
#pragma unroll
      for (int ci = 0; ci < 3; ci++) {
        float xv = xs[ci][ly+ky][lx+kx];
        const float4* wr = (const float4*)&wl[(ky*3+kx)*3+ci][cg*16];
#pragma unroll
        for (int q = 0; q < 4; q++) {
          float4 w4 = wr[q];
          acc[q*4+0] = fmaf(xv, w4.x, acc[q*4+0]);
          acc[q*4+1] = fmaf(xv, w4.y, acc[q*4+1]);
          acc[q*4+2] = fmaf(xv, w4.z, acc[q*4+2]);
          acc[q*4+3] = fmaf(xv, w4.w, acc[q*4+3]);
        }
      }
  int m_g = b*1024 + (y0+ly)*32 + lx;
  unsigned short zb[16];
#pragma unroll
  for (int q = 0; q < 4; q++) {
    int idx = m_g*64 + cg*16 + q*4;
    float vv[4] = {0.f,0.f,0.f,0.f}, ii[4] = {0.f,0.f,0.f,0.f};
    if (t != 0) {
      float4 v4 = *(const float4*)(v1+idx); float4 i4 = *(const float4*)(i1+idx);
      vv[0]=v4.x; vv[1]=v4.y; vv[2]=v4.z; vv[3]=v4.w;
      ii[0]=i4.x; ii[1]=i4.y; ii[2]=i4.z; ii[3]=i4.w;
    }
#pragma unroll
    for (int s = 0; s < 4; s++) {
      float vdec = vv[s] + DTM*((0.0f - vv[s]) + ii[s]);
      bool z = (vdec - VTH) > 0.0f;
      vv[s] = z ? 0.0f : vdec;
      ii[s] = SYN*ii[s] + acc[q*4+s];
      zb[q*4+s] = z ? 0x3F80 : 0;
    }
    *(float4*)(v1+idx) = make_float4(vv[0],vv[1],vv[2],vv[3]);
    *(float4*)(i1+idx) = make_float4(ii[0],ii[1],ii[2],ii[3]);
  }
  u32x4 za, zc;
  za[0]=zb[0]|((unsigned)zb[1]<<16); za[1]=zb[2]|((unsigned)zb[3]<<16);
  za[2]=zb[4]|((unsigned)zb[5]<<16); za[3]=zb[6]|((unsigned)zb[7]<<16);
  zc[0]=zb[8]|((unsigned)zb[9]<<16); zc[1]=zb[10]|((unsigned)zb[11]<<16);
  zc[2]=zb[12]|((unsigned)zb[13]<<16); zc[3]=zb[14]|((unsigned)zb[15]<<16);
  *(u32x4*)(z1 + m_g*64 + cg*16) = za;
  *(u32x4*)(z1 + m_g*64 + cg*16 + 8) = zc;
}

// ---------------------------------------------------------------------------
// Implicit-GEMM conv (3x3 SAME) over binary spikes, bf16 hi/mid/lo 3-digit
// MFMA. A staged once in LDS (XOR-swizzled); B fragments loaded per-lane
// DIRECTLY from global (L2) -- K-loop is barrier-free.
// Epilogue: fused LIF + (POOLZ) 2x2 max-pool of spikes via LDS OR-reduce,
// or (KSPLIT) atomic partial accumulation (exactly 2 adds/elem: deterministic).
// ---------------------------------------------------------------------------
template<int MF, int NF, int WM, int WN, int CIN_A, int WI, int HIM,
         int COUT, int CIN_SRC, int NT, bool KSPLIT, bool POOLZ>
__global__ __launch_bounds__(WM*WN*64, 1) void conv_lif(
    const unsigned short* __restrict__ zsrc,
    const unsigned short* __restrict__ wbh, const unsigned short* __restrict__ wbm,
    const unsigned short* __restrict__ wbl,
    float* __restrict__ vst, float* __restrict__ ist,
    unsigned short* __restrict__ zpool, float* __restrict__ partial, int t)
{
  constexpr int THREADS = WM*WN*64;
  constexpr int BM = WM*MF*16;
  constexpr int BN = WN*NF*16;
  constexpr int ROWS = BM/WI;
  constexpr int SLOTW = WI+2;
  constexpr int SLOTS = (ROWS+2)*SLOTW;
  constexpr int CPH = CIN_A/64;
  constexpr int P = 9*CPH;
  constexpr int MT_PER_B = (HIM*WI)/BM;
  constexpr int ACH = CIN_A/8;
  constexpr int ACHUNKS = SLOTS*ACH;
  constexpr int LDS_A = SLOTS*CIN_A*2;
  constexpr int LDS_Z = POOLZ ? BM*BN*2 : 16;
  constexpr int LDS_SZ = LDS_A > LDS_Z ? LDS_A : LDS_Z;
  static_assert(LDS_SZ <= 48*1024, "LDS");

  __shared__ __align__(16) char smem[LDS_SZ];

  int tid = threadIdx.x;
  int rem = blockIdx.x;
  int kh = 0;
  if constexpr (KSPLIT) { kh = rem & 1; rem >>= 1; }
  int nt = 0;
  if constexpr (NT > 1) { nt = rem % NT; rem /= NT; }
  int b = rem / MT_PER_B;
  int y0 = (rem % MT_PER_B) * ROWS;
  int lane = tid & 63;
  int wv = tid >> 6, wn = wv % WN, wm = wv / WN;
  int klane = (lane >> 4) * 8;
  int csrc0 = KSPLIT ? kh*128 : 0;

  // ---- stage A tile (once; t-invariant addresses) ----
  for (int ch = tid; ch < ACHUNKS; ch += THREADS) {
    int slot = ch / ACH, g = ch % ACH;
    int yr = slot / SLOTW, xr = slot % SLOTW;
    int y = y0 + yr - 1, xg = xr - 1;
    u32x4 val; val[0]=0; val[1]=0; val[2]=0; val[3]=0;
    if (y >= 0 && y < HIM && xg >= 0 && xg < WI)
      val = *(const u32x4*)(zsrc + ((long)(b*HIM + y)*WI + xg)*CIN_SRC + csrc0 + g*8);
    int addr = ((slot*CIN_A + g*8)*2) ^ ((slot & 7) << 4);
    *(u32x4*)(smem + addr) = val;
  }

  f32x4 acc[MF][NF];
#pragma unroll
  for (int mf = 0; mf < MF; mf++)
#pragma unroll
    for (int nf = 0; nf < NF; nf++) {
      acc[mf][nf][0]=0.f; acc[mf][nf][1]=0.f; acc[mf][nf][2]=0.f; acc[mf][nf][3]=0.f;
    }

  int grow0 = nt*BN + wn*NF*16 + (lane & 15);
  __syncthreads();

  // ---- barrier-free K loop ----
#pragma unroll 2
  for (int p = 0; p < P; p++) {
    int tap = p / CPH, cs = p % CPH;
    int dy = tap/3 - 1, dx = tap%3 - 1;
#pragma unroll
    for (int ks = 0; ks < 2; ks++) {
      short8 bh[NF], bm_[NF], bl[NF];
#pragma unroll
      for (int nf = 0; nf < NF; nf++) {
        long bo = ((long)tap*COUT + grow0 + nf*16)*CIN_SRC + csrc0 + cs*64 + ks*32 + klane;
        bh[nf]  = *(const short8*)(wbh + bo);
        bm_[nf] = *(const short8*)(wbm + bo);
        bl[nf]  = *(const short8*)(wbl + bo);
      }
      short8 a[MF];
#pragma unroll
      for (int mf = 0; mf < MF; mf++) {
        int pl = wm*MF*16 + mf*16 + (lane & 15);
        int yl = pl / WI, xl = pl % WI;
        int slot = (yl + dy + 1)*SLOTW + (xl + dx + 1);
        int addr = ((slot*CIN_A + cs*64 + ks*32 + klane)*2) ^ ((slot & 7) << 4);
        a[mf] = *(const short8*)(smem + addr);
      }
#pragma unroll
      for (int mf = 0; mf < MF; mf++)
#pragma unroll
        for (int nf = 0; nf < NF; nf++)
          acc[mf][nf] = __builtin_amdgcn_mfma_f32_16x16x32_bf16(a[mf], bh[nf], acc[mf][nf], 0, 0, 0);
#pragma unroll
      for (int mf = 0; mf < MF; mf++)
#pragma unroll
        for (int nf = 0; nf < NF; nf++)
          acc[mf][nf] = __builtin_amdgcn_mfma_f32_16x16x32_bf16(a[mf], bm_[nf], acc[mf][nf], 0, 0, 0);
#pragma unroll
      for (int mf = 0; mf < MF; mf++)
#pragma unroll
        for (int nf = 0; nf < NF; nf++)
          acc[mf][nf] = __builtin_amdgcn_mfma_f32_16x16x32_bf16(a[mf], bl[nf], acc[mf][nf], 0, 0, 0);
    }
  }

  // ---- epilogue: LIF state update (+ z into LDS for pooling) ----
  if constexpr (POOLZ) __syncthreads();   // smem (A) dead; reuse as z buffer
  unsigned short* zb = (unsigned short*)smem;
  int mbase = (b*HIM + y0)*WI;
#pragma unroll
  for (int mf = 0; mf < MF; mf++)
#pragma unroll
    for (int nf = 0; nf < NF; nf++) {
      int chn = wn*NF*16 + nf*16 + (lane & 15);
      int chg = nt*BN + chn;
#pragma unroll
      for (int r = 0; r < 4; r++) {
        int pix = wm*MF*16 + mf*16 + (lane>>4)*4 + r;
        long idx = (long)(mbase + pix)*COUT + chg;
        float cv = acc[mf][nf][r];
        if constexpr (KSPLIT) {
          atomicAdd(partial + idx, cv);
        } else {
          float vv = 0.f, ii = 0.f;
          if (t != 0) { vv = vst[idx]; ii = ist[idx]; }
          float vdec = vv + DTM*((0.0f - vv) + ii);
          bool z = (vdec - VTH) > 0.0f;
          vst[idx] = z ? 0.0f : vdec;
          ist[idx] = SYN*ii + cv;
          if constexpr (POOLZ) zb[pix*BN + chn] = z ? 0x3F80 : 0;
        }
      }
    }

  // ---- fused 2x2 max-pool of spikes (binary max == OR), coalesced write ----
  if constexpr (POOLZ) {
    __syncthreads();
    constexpr int WP = WI/2, PR = ROWS/2, CH16 = BN/8;
    for (int c = tid; c < PR*WP*CH16; c += THREADS) {
      int ppx = c / CH16, ck = c % CH16;
      int py = ppx / WP, px = ppx % WP;
      int b0 = ((2*py)*WI + 2*px)*BN + ck*8;
      u32x4 q0 = *(const u32x4*)(zb + b0);
      u32x4 q1 = *(const u32x4*)(zb + b0 + BN);
      u32x4 q2 = *(const u32x4*)(zb + b0 + WI*BN);
      u32x4 q3 = *(const u32x4*)(zb + b0 + WI*BN + BN);
      u32x4 vo = (q0|q1)|(q2|q3);
      long g = ((long)(b*(HIM/2) + (y0>>1) + py)*WP + px)*COUT + nt*BN + ck*8;
      *(u32x4*)(zpool + g) = vo;
    }
  }
}

// ---------------------------------------------------------------------------
// K5: LIF4 (from conv4 partial) + 2x2 pool + FC(4096->10) + LI + noise + max.
// ---------------------------------------------------------------------------
__global__ __launch_bounds__(256) void k5_lif4_fc(
    float* __restrict__ partial, float* __restrict__ v4, float* __restrict__ i4,
    const float* __restrict__ wfc, const float* __restrict__ noise,
    float* __restrict__ vl, float* __restrict__ il, float* __restrict__ dout, int t)
{
  __shared__ unsigned long long zbits[64][4];
  __shared__ unsigned long long pb[64];
  __shared__ float red[4][10];
  int tid = threadIdx.x, b = blockIdx.x;
  int px = tid >> 2, cq = tid & 3;
  long base = ((long)b*64 + px)*256 + cq*64;
  unsigned long long mask = 0ull;
#pragma unroll
  for (int q = 0; q < 16; q++) {
    float4 pv = *(const float4*)(partial + base + q*4);
    float vv[4] = {0.f,0.f,0.f,0.f}, ii[4] = {0.f,0.f,0.f,0.f};
    if (t != 0) {
      float4 v4v = *(const float4*)(v4 + base + q*4);
      float4 i4v = *(const float4*)(i4 + base + q*4);
      vv[0]=v4v.x; vv[1]=v4v.y; vv[2]=v4v.z; vv[3]=v4v.w;
      ii[0]=i4v.x; ii[1]=i4v.y; ii[2]=i4v.z; ii[3]=i4v.w;
    }
    float cv[4] = {pv.x, pv.y, pv.z, pv.w};
#pragma unroll
    for (int s = 0; s < 4; s++) {
      float vdec = vv[s] + DTM*((0.0f - vv[s]) + ii[s]);
      bool z = (vdec - VTH) > 0.0f;
      vv[s] = z ? 0.0f : vdec;
      ii[s] = SYN*ii[s] + cv[s];
      if (z) mask |= (1ull << (q*4 + s));
    }
    *(float4*)(v4 + base + q*4) = make_float4(vv[0],vv[1],vv[2],vv[3]);
    *(float4*)(i4 + base + q*4) = make_float4(ii[0],ii[1],ii[2],ii[3]);
    *(float4*)(partial + base + q*4) = make_float4(0.f,0.f,0.f,0.f);
  }
  zbits[px][cq] = mask;
  __syncthreads();
  if (tid < 64) {
    int py = tid >> 4, rm = tid & 15, pxx = rm >> 2, c4 = rm & 3;
    int p00 = (2*py)*8 + 2*pxx;
    pb[tid] = zbits[p00][c4] | zbits[p00+1][c4] | zbits[p00+8][c4] | zbits[p00+9][c4];
  }
  __syncthreads();
  float sums[10];
#pragma unroll
  for (int j = 0; j < 10; j++) sums[j] = 0.f;
  for (int q = 0; q < 16; q++) {
    int k = q*256 + tid;
    int c = k >> 4, s = k & 15, yy = s >> 2, xx = s & 3;
    unsigned long long bits = pb[yy*16 + xx*4 + (c >> 6)];
    if ((bits >> (c & 63)) & 1ull) {
#pragma unroll
      for (int j = 0; j < 10; j++) sums[j] += wfc[j*4096 + k];
    }
  }
#pragma unroll
  for (int j = 0; j < 10; j++) {
    float v = sums[j];
    for (int off = 32; off; off >>= 1) v += __shfl_xor(v, off);
    if ((tid & 63) == 0) red[tid>>6][j] = v;
  }
  __syncthreads();
  if (tid < 10) {
    float o = red[0][tid] + red[1][tid] + red[2][tid] + red[3][tid];
    float vo = 0.f, io = 0.f;
    if (t != 0) { vo = vl[b*10 + tid]; io = il[b*10 + tid]; }
    float vn = vo + DTM*((0.0f - vo) + io);
    float inw = SYN*io + o;
    vl[b*10 + tid] = vn; il[b*10 + tid] = inw;
    float volt = vn + 0.001f*noise[((long)t*32 + b)*10 + tid];
    dout[b*10 + tid] = (t == 0) ? volt : fmaxf(dout[b*10 + tid], volt);
  }
}

// ---------------------------------------------------------------------------
extern "C" void kernel_launch(void* const* d_in, const int* in_sizes, int n_in,
                              void* d_out, int out_size, void* d_ws, size_t ws_size,
                              hipStream_t stream)
{
  const float* x     = (const float*)d_in[0];
  const float* noise = (const float*)d_in[1];
  const float* w1    = (const float*)d_in[2];
  const float* w2    = (const float*)d_in[3];
  const float* w3    = (const float*)d_in[4];
  const float* w4    = (const float*)d_in[5];
  const float* wfc   = (const float*)d_in[6];
  float* dout = (float*)d_out;

  char* ws = (char*)d_ws;
  size_t off = 0;
  auto alloc = [&](size_t bytes) -> char* {
    char* p = ws + off;
    off = (off + bytes + 255) & ~(size_t)255;
    return p;
  };
  float* v1 = (float*)alloc(2097152u*4); float* i1 = (float*)alloc(2097152u*4);
  float* v2 = (float*)alloc(4194304u*4); float* i2 = (float*)alloc(4194304u*4);
  float* v3 = (float*)alloc(2097152u*4); float* i3 = (float*)alloc(2097152u*4);
  float* v4 = (float*)alloc(524288u*4);  float* i4 = (float*)alloc(524288u*4);
  unsigned short* z1  = (unsigned short*)alloc(2097152u*2);   // full-res spikes L1
  unsigned short* z2p = (unsigned short*)alloc(1048576u*2);   // pooled spikes L2: [32][16][16][128]
  unsigned short* z3p = (unsigned short*)alloc(524288u*2);    // pooled spikes L3: [32][8][8][256]
  float* partial = (float*)alloc(524288u*4);
  float* vl = (float*)alloc(1280);
  float* il = (float*)alloc(1280);
  unsigned short* wb2h = (unsigned short*)alloc(73728u*2);
  unsigned short* wb2m = (unsigned short*)alloc(73728u*2);
  unsigned short* wb2l = (unsigned short*)alloc(73728u*2);
  unsigned short* wb3h = (unsigned short*)alloc(294912u*2);
  unsigned short* wb3m = (unsigned short*)alloc(294912u*2);
  unsigned short* wb3l = (unsigned short*)alloc(294912u*2);
  unsigned short* wb4h = (unsigned short*)alloc(589824u*2);
  unsigned short* wb4m = (unsigned short*)alloc(589824u*2);
  unsigned short* wb4l = (unsigned short*)alloc(589824u*2);

  prep_kernel<<<5792, 256, 0, stream>>>(w2, w3, w4,
      wb2h, wb2m, wb2l, wb3h, wb3m, wb3l, wb4h, wb4m, wb4l, partial);

  for (int t = 0; t < 16; t++) {
    k1_conv1_lif<<<512, 256, 0, stream>>>(x, w1, v1, i1, z1, t);
    // conv2: 64->128 @32x32 full-res in, pooled-z out. BM=128,BN=128, 512thr, grid 256
    conv_lif<4,2,2,4, 64,32,32,128, 64,1,false,true><<<256, 512, 0, stream>>>(
        z1, wb2h, wb2m, wb2l, v2, i2, z2p, nullptr, t);
    // conv3: 128->256 @16x16 pooled in, pooled-z out. BM=64,BN=64, NT=4, grid 512
    conv_lif<4,1,1,4,128,16,16,256,128,4,false,true><<<512, 256, 0, stream>>>(
        z2p, wb3h, wb3m, wb3l, v3, i3, z3p, nullptr, t);
    // conv4: 256->256 @8x8 pooled in, KSPLIT=2 atomic partial. BM=32,BN=64, NT=4, grid 512
    conv_lif<2,1,1,4,128, 8, 8,256,256,4,true,false><<<512, 256, 0, stream>>>(
        z3p, wb4h, wb4m, wb4l, nullptr, nullptr, nullptr, partial, t);
    k5_lif4_fc<<<32, 256, 0, stream>>>(partial, v4, i4, wfc, noise, vl, il, dout, t);
  }
}

// Round 7
// 2321.543 us; speedup vs baseline: 1.0158x; 1.0143x over previous
//
#include <hip/hip_runtime.h>

typedef __attribute__((ext_vector_type(8))) short short8;
typedef __attribute__((ext_vector_type(4))) float f32x4;
typedef __attribute__((ext_vector_type(4))) unsigned int u32x4;

#define DEV static __device__ __forceinline__

DEV unsigned short f2bf(float f){
  unsigned int u = __float_as_uint(f);
  u += 0x7FFFu + ((u >> 16) & 1u);
  return (unsigned short)(u >> 16);
}
DEV float bf2f(unsigned short h){ return __uint_as_float(((unsigned int)h) << 16); }

#define DTM 0.1f   /* DT*TAU_MEM_INV */
#define SYN 0.8f   /* 1 - DT*TAU_SYN_INV */
#define VTH 0.2f

// ---------------------------------------------------------------------------
// prep: build [tap][co][ci] bf16 hi/mid/lo weight digits, zero conv4 partial.
// ---------------------------------------------------------------------------
__global__ __launch_bounds__(256) void prep_kernel(
    const float* __restrict__ w2, const float* __restrict__ w3, const float* __restrict__ w4,
    unsigned short* __restrict__ wb2h, unsigned short* __restrict__ wb2m, unsigned short* __restrict__ wb2l,
    unsigned short* __restrict__ wb3h, unsigned short* __restrict__ wb3m, unsigned short* __restrict__ wb3l,
    unsigned short* __restrict__ wb4h, unsigned short* __restrict__ wb4m, unsigned short* __restrict__ wb4l,
    float* __restrict__ partial)
{
  const int N2 = 9*128*64, N3 = 9*256*128, N4 = 9*256*256, NP = 2048*256;
  int tid = blockIdx.x*256 + threadIdx.x;
  if (tid < N2) {
    int tap = tid/(128*64), r = tid%(128*64), co = r>>6, ci = r&63;
    float w = w2[(co*64+ci)*9 + tap];
    unsigned short h = f2bf(w);       float r1 = w - bf2f(h);
    unsigned short m = f2bf(r1);      float r2 = r1 - bf2f(m);
    wb2h[tid] = h; wb2m[tid] = m; wb2l[tid] = f2bf(r2);
    return;
  }
  tid -= N2;
  if (tid < N3) {
    int tap = tid/(256*128), r = tid%(256*128), co = r>>7, ci = r&127;
    float w = w3[(co*128+ci)*9 + tap];
    unsigned short h = f2bf(w);       float r1 = w - bf2f(h);
    unsigned short m = f2bf(r1);      float r2 = r1 - bf2f(m);
    wb3h[tid] = h; wb3m[tid] = m; wb3l[tid] = f2bf(r2);
    return;
  }
  tid -= N3;
  if (tid < N4) {
    int tap = tid/(256*256), r = tid%(256*256), co = r>>8, ci = r&255;
    float w = w4[(co*256+ci)*9 + tap];
    unsigned short h = f2bf(w);       float r1 = w - bf2f(h);
    unsigned short m = f2bf(r1);      float r2 = r1 - bf2f(m);
    wb4h[tid] = h; wb4m[tid] = m; wb4l[tid] = f2bf(r2);
    return;
  }
  tid -= N4;
  if (tid < NP) partial[tid] = 0.f;
}

// ---------------------------------------------------------------------------
// K1: conv1 (fp32 direct, 3->64, 3x3 SAME) + LIF1. grid 512 = 32 imgs x 16 row-pairs
// ---------------------------------------------------------------------------
__global__ __launch_bounds__(256) void k1_conv1_lif(
    const float* __restrict__ x, const float* __restrict__ w1,
    float* __restrict__ v1, float* __restrict__ i1,
    unsigned short* __restrict__ z1, int t)
{
  __shared__ float xs[3][4][34];
  __shared__ float wl[27][64];
  int tid = threadIdx.x;
  int b = blockIdx.x >> 4, y0 = (blockIdx.x & 15) * 2;
  for (int e = tid; e < 3*4*34; e += 256) {
    int ci = e/136, r2 = e%136, r = r2/34, xi = r2%34;
    int y = y0 - 1 + r, xg = xi - 1;
    float v = 0.f;
    if (y >= 0 && y < 32 && xg >= 0 && xg < 32)
      v = x[((t*32 + b)*3 + ci)*1024 + y*32 + xg];
    xs[ci][r][xi] = v;
  }
  for (int e = tid; e < 27*64; e += 256) {
    int row = e >> 6, co = e & 63;
    int ci = row % 3, tap = row / 3, ky = tap/3, kx = tap%3;
    wl[row][co] = w1[((co*3+ci)*3+ky)*3+kx];
  }
  __syncthreads();
  int px = tid >> 2, cg = tid & 3;
  int ly = px >> 5, lx = px & 31;
  float acc[16];
#pragma unroll
  for (int q = 0; q < 16; q++) acc[q] = 0.f;
#pragma unroll
  for (int ky = 0; ky < 3; ky++)
#pragma unroll
    for (int kx = 0; kx < 3; kx++)
#pragma unroll
      for (int ci = 0; ci < 3; ci++) {
        float xv = xs[ci][ly+ky][lx+kx];
        const float4* wr = (const float4*)&wl[(ky*3+kx)*3+ci][cg*16];
#pragma unroll
        for (int q = 0; q < 4; q++) {
          float4 w4 = wr[q];
          acc[q*4+0] = fmaf(xv, w4.x, acc[q*4+0]);
          acc[q*4+1] = fmaf(xv, w4.y, acc[q*4+1]);
          acc[q*4+2] = fmaf(xv, w4.z, acc[q*4+2]);
          acc[q*4+3] = fmaf(xv, w4.w, acc[q*4+3]);
        }
      }
  int m_g = b*1024 + (y0+ly)*32 + lx;
  unsigned short zb[16];
#pragma unroll
  for (int q = 0; q < 4; q++) {
    int idx = m_g*64 + cg*16 + q*4;
    float vv[4] = {0.f,0.f,0.f,0.f}, ii[4] = {0.f,0.f,0.f,0.f};
    if (t != 0) {
      float4 v4 = *(const float4*)(v1+idx); float4 i4 = *(const float4*)(i1+idx);
      vv[0]=v4.x; vv[1]=v4.y; vv[2]=v4.z; vv[3]=v4.w;
      ii[0]=i4.x; ii[1]=i4.y; ii[2]=i4.z; ii[3]=i4.w;
    }
#pragma unroll
    for (int s = 0; s < 4; s++) {
      float vdec = vv[s] + DTM*((0.0f - vv[s]) + ii[s]);
      bool z = (vdec - VTH) > 0.0f;
      vv[s] = z ? 0.0f : vdec;
      ii[s] = SYN*ii[s] + acc[q*4+s];
      zb[q*4+s] = z ? 0x3F80 : 0;
    }
    *(float4*)(v1+idx) = make_float4(vv[0],vv[1],vv[2],vv[3]);
    *(float4*)(i1+idx) = make_float4(ii[0],ii[1],ii[2],ii[3]);
  }
  u32x4 za, zc;
  za[0]=zb[0]|((unsigned)zb[1]<<16); za[1]=zb[2]|((unsigned)zb[3]<<16);
  za[2]=zb[4]|((unsigned)zb[5]<<16); za[3]=zb[6]|((unsigned)zb[7]<<16);
  zc[0]=zb[8]|((unsigned)zb[9]<<16); zc[1]=zb[10]|((unsigned)zb[11]<<16);
  zc[2]=zb[12]|((unsigned)zb[13]<<16); zc[3]=zb[14]|((unsigned)zb[15]<<16);
  *(u32x4*)(z1 + m_g*64 + cg*16) = za;
  *(u32x4*)(z1 + m_g*64 + cg*16 + 8) = zc;
}

// ---------------------------------------------------------------------------
// Implicit-GEMM conv (3x3 SAME) over binary spikes, bf16 hi/mid/lo 3-digit
// MFMA. A staged once in LDS (XOR-swizzled). B double-buffered in LDS, staged
// global->reg->LDS per K=32 stage, ONE barrier per stage (T3-lite pipeline).
// 256 thr = 4 waves (WM=1, WN=4, NF=1): BM = MF*16, BN = 64.
// Epilogue: fused LIF + optional 2x2 spike max-pool (binary max == OR), or
// KSPLIT=2 atomic partial accumulation (2 adds/elem: commutative -> determ.).
// ---------------------------------------------------------------------------
template<int MF, int CIN_A, int WI, int HIM, int COUT, int CIN_SRC,
         int NT, bool KSPLIT, bool POOLZ>
__global__ __launch_bounds__(256, 3) void conv_lif(
    const unsigned short* __restrict__ zsrc,
    const unsigned short* __restrict__ wbh, const unsigned short* __restrict__ wbm,
    const unsigned short* __restrict__ wbl,
    float* __restrict__ vst, float* __restrict__ ist,
    unsigned short* __restrict__ zpool, float* __restrict__ partial, int t)
{
  constexpr int THREADS = 256;
  constexpr int BM = MF*16;
  constexpr int BN = 64;
  constexpr int ROWS = BM/WI;
  constexpr int SLOTW = WI+2;
  constexpr int SLOTS = (ROWS+2)*SLOTW;
  constexpr int CPH = CIN_A/64;
  constexpr int P = 9*CPH;
  constexpr int S = P*2;                 // K=32 stages
  constexpr int MT_PER_B = (HIM*WI)/BM;
  constexpr int ACH = CIN_A/8;
  constexpr int ACHUNKS = SLOTS*ACH;
  constexpr int ABYTES = SLOTS*CIN_A*2;
  constexpr int ZBYTES = POOLZ ? BM*BN*2 : 16;
  constexpr int AREG = ABYTES > ZBYTES ? ABYTES : ZBYTES;
  constexpr int BSTAGE = BN*32*2*3;      // 12288 B (3 digits x 4KB)
  static_assert(AREG + 2*BSTAGE <= 64*1024, "LDS");

  __shared__ __align__(16) char smem[AREG + 2*BSTAGE];

  int tid = threadIdx.x;
  int rem = blockIdx.x;
  int kh = 0;
  if constexpr (KSPLIT) { kh = rem & 1; rem >>= 1; }
  int nt = 0;
  if constexpr (NT > 1) { nt = rem % NT; rem /= NT; }
  int b = rem / MT_PER_B;
  int y0 = (rem % MT_PER_B) * ROWS;
  int lane = tid & 63, wn = tid >> 6;
  int csrc0 = KSPLIT ? kh*CIN_A : 0;

  // ---- stage A tile (once) ----
  for (int ch = tid; ch < ACHUNKS; ch += THREADS) {
    int slot = ch / ACH, g = ch % ACH;
    int yr = slot / SLOTW, xr = slot % SLOTW;
    int y = y0 + yr - 1, xg = xr - 1;
    u32x4 val; val[0]=0; val[1]=0; val[2]=0; val[3]=0;
    if (y >= 0 && y < HIM && xg >= 0 && xg < WI)
      val = *(const u32x4*)(zsrc + ((long)(b*HIM + y)*WI + xg)*CIN_SRC + csrc0 + g*8);
    int addr = ((slot*CIN_A + g*8)*2) ^ ((slot & 7) << 4);
    *(u32x4*)(smem + addr) = val;
  }

  // ---- B staging setup: thread (co=tid>>2, g=tid&3) moves one 16B chunk/digit
  int bco = tid >> 2, bg = tid & 3;
  int bwaddr = AREG + bco*64 + ((bg ^ (bco & 3)) << 4);
  long bgbase = (long)(nt*BN + bco)*CIN_SRC + csrc0 + bg*8;
  u32x4 brh, brm, brl;
  auto stage_load = [&](int s) {
    int p = s >> 1, ks2 = s & 1;
    int tap = p / CPH, cs = p % CPH;
    long off = (long)tap*COUT*CIN_SRC + bgbase + cs*64 + ks2*32;
    brh = *(const u32x4*)(wbh + off);
    brm = *(const u32x4*)(wbm + off);
    brl = *(const u32x4*)(wbl + off);
  };
  auto stage_store = [&](int buf) {
    char* dst = smem + bwaddr + buf*BSTAGE;
    *(u32x4*)(dst)        = brh;
    *(u32x4*)(dst + 4096) = brm;
    *(u32x4*)(dst + 8192) = brl;
  };

  // B fragment read address (loop-invariant)
  int brrow = wn*16 + (lane & 15);
  int brd = AREG + brrow*64 + (((lane >> 4) ^ (brrow & 3)) << 4);

  f32x4 acc[MF];
#pragma unroll
  for (int mf = 0; mf < MF; mf++) {
    acc[mf][0]=0.f; acc[mf][1]=0.f; acc[mf][2]=0.f; acc[mf][3]=0.f;
  }

  stage_load(0); stage_store(0);
  __syncthreads();

  // ---- K loop: one barrier per stage, B(s+1) staged under MFMA(s) ----
#pragma unroll 2
  for (int s = 0; s < S; s++) {
    if (s+1 < S) stage_load(s+1);
    int p = s >> 1, ks2 = s & 1;
    int tap = p / CPH, cs = p % CPH;
    int dy = tap/3 - 1, dx = tap%3 - 1;
    const char* bbuf = smem + (s & 1)*BSTAGE;
    short8 bh  = *(const short8*)(bbuf + brd);
    short8 bm_ = *(const short8*)(bbuf + brd + 4096);
    short8 bl_ = *(const short8*)(bbuf + brd + 8192);
    int choff2 = (cs*64 + ks2*32 + (lane >> 4)*8)*2;
    short8 a[MF];
#pragma unroll
    for (int mf = 0; mf < MF; mf++) {
      int pl = mf*16 + (lane & 15);
      int yl = pl / WI, xl = pl % WI;
      int slot = (yl + dy + 1)*SLOTW + (xl + dx + 1);
      int addr = ((slot*CIN_A)*2 + choff2) ^ ((slot & 7) << 4);
      a[mf] = *(const short8*)(smem + addr);
    }
#pragma unroll
    for (int mf = 0; mf < MF; mf++)
      acc[mf] = __builtin_amdgcn_mfma_f32_16x16x32_bf16(a[mf], bh, acc[mf], 0, 0, 0);
#pragma unroll
    for (int mf = 0; mf < MF; mf++)
      acc[mf] = __builtin_amdgcn_mfma_f32_16x16x32_bf16(a[mf], bm_, acc[mf], 0, 0, 0);
#pragma unroll
    for (int mf = 0; mf < MF; mf++)
      acc[mf] = __builtin_amdgcn_mfma_f32_16x16x32_bf16(a[mf], bl_, acc[mf], 0, 0, 0);
    if (s+1 < S) stage_store((s+1) & 1);
    __syncthreads();
  }

  // ---- epilogue: LIF state update (+ z into LDS for pooling) ----
  unsigned short* zb = (unsigned short*)smem;
  int mbase = (b*HIM + y0)*WI;
  int chn = wn*16 + (lane & 15);
  int chg = nt*BN + chn;
#pragma unroll
  for (int mf = 0; mf < MF; mf++) {
#pragma unroll
    for (int r = 0; r < 4; r++) {
      int pix = mf*16 + (lane >> 4)*4 + r;
      long idx = (long)(mbase + pix)*COUT + chg;
      float cv = acc[mf][r];
      if constexpr (KSPLIT) {
        atomicAdd(partial + idx, cv);
      } else {
        float vv = 0.f, ii = 0.f;
        if (t != 0) { vv = vst[idx]; ii = ist[idx]; }
        float vdec = vv + DTM*((0.0f - vv) + ii);
        bool z = (vdec - VTH) > 0.0f;
        vst[idx] = z ? 0.0f : vdec;
        ist[idx] = SYN*ii + cv;
        if constexpr (POOLZ) zb[pix*BN + chn] = z ? 0x3F80 : 0;
      }
    }
  }

  // ---- fused 2x2 max-pool of spikes (binary max == OR), coalesced write ----
  if constexpr (POOLZ) {
    __syncthreads();
    constexpr int WP = WI/2, PR = ROWS/2, CH16 = BN/8;
    for (int c = tid; c < PR*WP*CH16; c += THREADS) {
      int ppx = c / CH16, ck = c % CH16;
      int py = ppx / WP, px = ppx % WP;
      int b0 = ((2*py)*WI + 2*px)*BN + ck*8;
      u32x4 q0 = *(const u32x4*)(zb + b0);
      u32x4 q1 = *(const u32x4*)(zb + b0 + BN);
      u32x4 q2 = *(const u32x4*)(zb + b0 + WI*BN);
      u32x4 q3 = *(const u32x4*)(zb + b0 + WI*BN + BN);
      u32x4 vo = (q0|q1)|(q2|q3);
      long g = ((long)(b*(HIM/2) + (y0>>1) + py)*WP + px)*COUT + nt*BN + ck*8;
      *(u32x4*)(zpool + g) = vo;
    }
  }
}

// ---------------------------------------------------------------------------
// K5: LIF4 (from conv4 partial) + 2x2 pool + FC(4096->10) + LI + noise + max.
// 512 threads, one block per image. Re-zeroes partial for the next step.
// ---------------------------------------------------------------------------
__global__ __launch_bounds__(512) void k5_lif4_fc(
    float* __restrict__ partial, float* __restrict__ v4, float* __restrict__ i4,
    const float* __restrict__ wfc, const float* __restrict__ noise,
    float* __restrict__ vl, float* __restrict__ il, float* __restrict__ dout, int t)
{
  __shared__ unsigned zbits[64][8];
  __shared__ unsigned pb[16][8];
  __shared__ float red[8][10];
  int tid = threadIdx.x, b = blockIdx.x;
  int px = tid >> 3, c8 = tid & 7;      // 64 px x 8 groups of 32 ch
  long base = ((long)b*64 + px)*256 + c8*32;
  unsigned mask = 0u;
#pragma unroll
  for (int q = 0; q < 8; q++) {
    float4 pv = *(const float4*)(partial + base + q*4);
    float vv[4] = {0.f,0.f,0.f,0.f}, ii[4] = {0.f,0.f,0.f,0.f};
    if (t != 0) {
      float4 v4v = *(const float4*)(v4 + base + q*4);
      float4 i4v = *(const float4*)(i4 + base + q*4);
      vv[0]=v4v.x; vv[1]=v4v.y; vv[2]=v4v.z; vv[3]=v4v.w;
      ii[0]=i4v.x; ii[1]=i4v.y; ii[2]=i4v.z; ii[3]=i4v.w;
    }
    float cv[4] = {pv.x, pv.y, pv.z, pv.w};
#pragma unroll
    for (int s = 0; s < 4; s++) {
      float vdec = vv[s] + DTM*((0.0f - vv[s]) + ii[s]);
      bool z = (vdec - VTH) > 0.0f;
      vv[s] = z ? 0.0f : vdec;
      ii[s] = SYN*ii[s] + cv[s];
      if (z) mask |= (1u << (q*4 + s));
    }
    *(float4*)(v4 + base + q*4) = make_float4(vv[0],vv[1],vv[2],vv[3]);
    *(float4*)(i4 + base + q*4) = make_float4(ii[0],ii[1],ii[2],ii[3]);
    *(float4*)(partial + base + q*4) = make_float4(0.f,0.f,0.f,0.f);
  }
  zbits[px][c8] = mask;
  __syncthreads();
  if (tid < 128) {
    int pp = tid >> 3, grp = tid & 7;
    int py = pp >> 2, pxx = pp & 3;
    int p00 = (2*py)*8 + 2*pxx;
    pb[pp][grp] = zbits[p00][grp] | zbits[p00+1][grp] | zbits[p00+8][grp] | zbits[p00+9][grp];
  }
  __syncthreads();
  float sums[10];
#pragma unroll
  for (int j = 0; j < 10; j++) sums[j] = 0.f;
#pragma unroll
  for (int q = 0; q < 8; q++) {
    int k = q*512 + tid;
    int c = k >> 4, s = k & 15;
    if ((pb[s][c >> 5] >> (c & 31)) & 1u) {
#pragma unroll
      for (int j = 0; j < 10; j++) sums[j] += wfc[j*4096 + k];
    }
  }
#pragma unroll
  for (int j = 0; j < 10; j++) {
    float v = sums[j];
    for (int off = 32; off; off >>= 1) v += __shfl_xor(v, off);
    if ((tid & 63) == 0) red[tid >> 6][j] = v;
  }
  __syncthreads();
  if (tid < 10) {
    float o = 0.f;
#pragma unroll
    for (int w = 0; w < 8; w++) o += red[w][tid];
    float vo = 0.f, io = 0.f;
    if (t != 0) { vo = vl[b*10 + tid]; io = il[b*10 + tid]; }
    float vn = vo + DTM*((0.0f - vo) + io);
    float inw = SYN*io + o;
    vl[b*10 + tid] = vn; il[b*10 + tid] = inw;
    float volt = vn + 0.001f*noise[((long)t*32 + b)*10 + tid];
    dout[b*10 + tid] = (t == 0) ? volt : fmaxf(dout[b*10 + tid], volt);
  }
}

// ---------------------------------------------------------------------------
extern "C" void kernel_launch(void* const* d_in, const int* in_sizes, int n_in,
                              void* d_out, int out_size, void* d_ws, size_t ws_size,
                              hipStream_t stream)
{
  const float* x     = (const float*)d_in[0];
  const float* noise = (const float*)d_in[1];
  const float* w1    = (const float*)d_in[2];
  const float* w2    = (const float*)d_in[3];
  const float* w3    = (const float*)d_in[4];
  const float* w4    = (const float*)d_in[5];
  const float* wfc   = (const float*)d_in[6];
  float* dout = (float*)d_out;

  char* ws = (char*)d_ws;
  size_t off = 0;
  auto alloc = [&](size_t bytes) -> char* {
    char* p = ws + off;
    off = (off + bytes + 255) & ~(size_t)255;
    return p;
  };
  float* v1 = (float*)alloc(2097152u*4); float* i1 = (float*)alloc(2097152u*4);
  float* v2 = (float*)alloc(4194304u*4); float* i2 = (float*)alloc(4194304u*4);
  float* v3 = (float*)alloc(2097152u*4); float* i3 = (float*)alloc(2097152u*4);
  float* v4 = (float*)alloc(524288u*4);  float* i4 = (float*)alloc(524288u*4);
  unsigned short* z1  = (unsigned short*)alloc(2097152u*2);   // full-res spikes L1
  unsigned short* z2p = (unsigned short*)alloc(1048576u*2);   // pooled spikes L2: [32][16][16][128]
  unsigned short* z3p = (unsigned short*)alloc(524288u*2);    // pooled spikes L3: [32][8][8][256]
  float* partial = (float*)alloc(524288u*4);
  float* vl = (float*)alloc(1280);
  float* il = (float*)alloc(1280);
  unsigned short* wb2h = (unsigned short*)alloc(73728u*2);
  unsigned short* wb2m = (unsigned short*)alloc(73728u*2);
  unsigned short* wb2l = (unsigned short*)alloc(73728u*2);
  unsigned short* wb3h = (unsigned short*)alloc(294912u*2);
  unsigned short* wb3m = (unsigned short*)alloc(294912u*2);
  unsigned short* wb3l = (unsigned short*)alloc(294912u*2);
  unsigned short* wb4h = (unsigned short*)alloc(589824u*2);
  unsigned short* wb4m = (unsigned short*)alloc(589824u*2);
  unsigned short* wb4l = (unsigned short*)alloc(589824u*2);

  prep_kernel<<<5792, 256, 0, stream>>>(w2, w3, w4,
      wb2h, wb2m, wb2l, wb3h, wb3m, wb3l, wb4h, wb4m, wb4l, partial);

  for (int t = 0; t < 16; t++) {
    k1_conv1_lif<<<512, 256, 0, stream>>>(x, w1, v1, i1, z1, t);
    // conv2: 64->128 @32x32, BM=64 BN=64 NT=2, grid 1024 (12 waves/CU resident)
    conv_lif<4, 64,32,32,128, 64,2,false,true><<<1024, 256, 0, stream>>>(
        z1, wb2h, wb2m, wb2l, v2, i2, z2p, nullptr, t);
    // conv3: 128->256 @16x16 pooled-in, BM=32 BN=64 NT=4, grid 1024
    conv_lif<2,128,16,16,256,128,4,false,true><<<1024, 256, 0, stream>>>(
        z2p, wb3h, wb3m, wb3l, v3, i3, z3p, nullptr, t);
    // conv4: 256->256 @8x8 pooled-in, BM=32 BN=64 NT=4 KSPLIT=2, grid 512
    conv_lif<2,128, 8, 8,256,256,4,true,false><<<512, 256, 0, stream>>>(
        z3p, wb4h, wb4m, wb4l, nullptr, nullptr, nullptr, partial, t);
    k5_lif4_fc<<<32, 512, 0, stream>>>(partial, v4, i4, wfc, noise, vl, il, dout, t);
  }
}

// Round 8
// 2312.995 us; speedup vs baseline: 1.0195x; 1.0037x over previous
//
#include <hip/hip_runtime.h>

typedef __attribute__((ext_vector_type(8))) short short8;
typedef __attribute__((ext_vector_type(4))) float f32x4;
typedef __attribute__((ext_vector_type(4))) unsigned int u32x4;

#define DEV static __device__ __forceinline__

DEV unsigned short f2bf(float f){
  unsigned int u = __float_as_uint(f);
  u += 0x7FFFu + ((u >> 16) & 1u);
  return (unsigned short)(u >> 16);
}
DEV float bf2f(unsigned short h){ return __uint_as_float(((unsigned int)h) << 16); }

#define DTM 0.1f   /* DT*TAU_MEM_INV */
#define SYN 0.8f   /* 1 - DT*TAU_SYN_INV */
#define VTH 0.2f

// ---------------------------------------------------------------------------
// prep: weights -> MFMA-fragment-major bf16 hi/mid/lo digit layout:
//   dst[((s*4 + kg)*COUT + co)*8 + j]  = digit(w[co][ci(s,kg,j)][tap(s)])
// so a wave's per-stage B fragment load (lanes: co=lane&15, kg=lane>>4) is
// 16 x contiguous 16B = 256B per 128B-line-aligned region (L2-friendly).
// Also zeroes the conv4 partial buffer.
// ---------------------------------------------------------------------------
__global__ __launch_bounds__(256) void prep_kernel(
    const float* __restrict__ w2, const float* __restrict__ w3, const float* __restrict__ w4,
    unsigned short* __restrict__ wb2h, unsigned short* __restrict__ wb2m, unsigned short* __restrict__ wb2l,
    unsigned short* __restrict__ wb3h, unsigned short* __restrict__ wb3m, unsigned short* __restrict__ wb3l,
    unsigned short* __restrict__ wb4h, unsigned short* __restrict__ wb4m, unsigned short* __restrict__ wb4l,
    float* __restrict__ partial)
{
  const int N2 = 9*128*64, N3 = 9*256*128, N4 = 9*256*256, NP = 2048*256;
  int tid = blockIdx.x*256 + threadIdx.x;
  if (tid < N2) {           // conv2: CIN=64, CPH=1, S=18
    int j = tid & 7, co = (tid >> 3) & 127, q = (tid >> 3) >> 7;
    int kg = q & 3, s = q >> 2;
    int tap = s >> 1, ks = s & 1;
    int ci = ks*32 + kg*8 + j;
    float w = w2[(co*64 + ci)*9 + tap];
    unsigned short h = f2bf(w);   float r1 = w - bf2f(h);
    unsigned short m = f2bf(r1);  float r2 = r1 - bf2f(m);
    wb2h[tid] = h; wb2m[tid] = m; wb2l[tid] = f2bf(r2);
    return;
  }
  tid -= N2;
  if (tid < N3) {           // conv3: CIN=128, CPH=2, S=36
    int j = tid & 7, co = (tid >> 3) & 255, q = (tid >> 3) >> 8;
    int kg = q & 3, s = q >> 2;
    int p = s >> 1, ks = s & 1, tap = p >> 1, cs = p & 1;
    int ci = cs*64 + ks*32 + kg*8 + j;
    float w = w3[(co*128 + ci)*9 + tap];
    unsigned short h = f2bf(w);   float r1 = w - bf2f(h);
    unsigned short m = f2bf(r1);  float r2 = r1 - bf2f(m);
    wb3h[tid] = h; wb3m[tid] = m; wb3l[tid] = f2bf(r2);
    return;
  }
  tid -= N3;
  if (tid < N4) {           // conv4: CIN=256 as 2 halves of 128, S_local=36, sg in [0,72)
    int j = tid & 7, co = (tid >> 3) & 255, q = (tid >> 3) >> 8;
    int kg = q & 3, sg = q >> 2;
    int hh = sg / 36, sl = sg % 36;
    int p = sl >> 1, ks = sl & 1, tap = p >> 1, cs = p & 1;
    int ci = hh*128 + cs*64 + ks*32 + kg*8 + j;
    float w = w4[(co*256 + ci)*9 + tap];
    unsigned short h = f2bf(w);   float r1 = w - bf2f(h);
    unsigned short m = f2bf(r1);  float r2 = r1 - bf2f(m);
    wb4h[tid] = h; wb4m[tid] = m; wb4l[tid] = f2bf(r2);
    return;
  }
  tid -= N4;
  if (tid < NP) partial[tid] = 0.f;
}

// ---------------------------------------------------------------------------
// K1: conv1 (fp32 direct, 3->64, 3x3 SAME) + LIF1. grid 512 = 32 imgs x 16 row-pairs
// ---------------------------------------------------------------------------
__global__ __launch_bounds__(256) void k1_conv1_lif(
    const float* __restrict__ x, const float* __restrict__ w1,
    float* __restrict__ v1, float* __restrict__ i1,
    unsigned short* __restrict__ z1, int t)
{
  __shared__ float xs[3][4][34];
  __shared__ float wl[27][64];
  int tid = threadIdx.x;
  int b = blockIdx.x >> 4, y0 = (blockIdx.x & 15) * 2;
  for (int e = tid; e < 3*4*34; e += 256) {
    int ci = e/136, r2 = e%136, r = r2/34, xi = r2%34;
    int y = y0 - 1 + r, xg = xi - 1;
    float v = 0.f;
    if (y >= 0 && y < 32 && xg >= 0 && xg < 32)
      v = x[((t*32 + b)*3 + ci)*1024 + y*32 + xg];
    xs[ci][r][xi] = v;
  }
  for (int e = tid; e < 27*64; e += 256) {
    int row = e >> 6, co = e & 63;
    int ci = row % 3, tap = row / 3, ky = tap/3, kx = tap%3;
    wl[row][co] = w1[((co*3+ci)*3+ky)*3+kx];
  }
  __syncthreads();
  int px = tid >> 2, cg = tid & 3;
  int ly = px >> 5, lx = px & 31;
  float acc[16];
#pragma unroll
  for (int q = 0; q < 16; q++) acc[q] = 0.f;
#pragma unroll
  for (int ky = 0; ky < 3; ky++)
#pragma unroll
    for (int kx = 0; kx < 3; kx++)
#pragma unroll
      for (int ci = 0; ci < 3; ci++) {
        float xv = xs[ci][ly+ky][lx+kx];
        const float4* wr = (const float4*)&wl[(ky*3+kx)*3+ci][cg*16];
#pragma unroll
        for (int q = 0; q < 4; q++) {
          float4 w4 = wr[q];
          acc[q*4+0] = fmaf(xv, w4.x, acc[q*4+0]);
          acc[q*4+1] = fmaf(xv, w4.y, acc[q*4+1]);
          acc[q*4+2] = fmaf(xv, w4.z, acc[q*4+2]);
          acc[q*4+3] = fmaf(xv, w4.w, acc[q*4+3]);
        }
      }
  int m_g = b*1024 + (y0+ly)*32 + lx;
  unsigned short zb[16];
#pragma unroll
  for (int q = 0; q < 4; q++) {
    int idx = m_g*64 + cg*16 + q*4;
    float vv[4] = {0.f,0.f,0.f,0.f}, ii[4] = {0.f,0.f,0.f,0.f};
    if (t != 0) {
      float4 v4 = *(const float4*)(v1+idx); float4 i4 = *(const float4*)(i1+idx);
      vv[0]=v4.x; vv[1]=v4.y; vv[2]=v4.z; vv[3]=v4.w;
      ii[0]=i4.x; ii[1]=i4.y; ii[2]=i4.z; ii[3]=i4.w;
    }
#pragma unroll
    for (int s = 0; s < 4; s++) {
      float vdec = vv[s] + DTM*((0.0f - vv[s]) + ii[s]);
      bool z = (vdec - VTH) > 0.0f;
      vv[s] = z ? 0.0f : vdec;
      ii[s] = SYN*ii[s] + acc[q*4+s];
      zb[q*4+s] = z ? 0x3F80 : 0;
    }
    *(float4*)(v1+idx) = make_float4(vv[0],vv[1],vv[2],vv[3]);
    *(float4*)(i1+idx) = make_float4(ii[0],ii[1],ii[2],ii[3]);
  }
  u32x4 za, zc;
  za[0]=zb[0]|((unsigned)zb[1]<<16); za[1]=zb[2]|((unsigned)zb[3]<<16);
  za[2]=zb[4]|((unsigned)zb[5]<<16); za[3]=zb[6]|((unsigned)zb[7]<<16);
  zc[0]=zb[8]|((unsigned)zb[9]<<16); zc[1]=zb[10]|((unsigned)zb[11]<<16);
  zc[2]=zb[12]|((unsigned)zb[13]<<16); zc[3]=zb[14]|((unsigned)zb[15]<<16);
  *(u32x4*)(z1 + m_g*64 + cg*16) = za;
  *(u32x4*)(z1 + m_g*64 + cg*16 + 8) = zc;
}

// ---------------------------------------------------------------------------
// Implicit-GEMM conv (3x3 SAME) over binary spikes, bf16 hi/mid/lo 3-digit
// MFMA. A staged once in LDS (XOR-swizzled, conflict-free); B fragments come
// per-lane from global in fragment-major layout (L2-resident, coalesced
// 256B/wave) with explicit depth-2 register prefetch. K-loop has NO barriers.
// Epilogue: fused LIF + optional 2x2 spike max-pool (binary max == OR), or
// KSPLIT=2 atomic partial accumulation (2 adds/elem, commutative -> determ.).
// ---------------------------------------------------------------------------
template<int MF, int CIN_A, int WI, int HIM, int COUT, int CIN_SRC,
         int NT, bool KSPLIT, bool POOLZ>
__global__ __launch_bounds__(256, 4) void conv_lif(
    const unsigned short* __restrict__ zsrc,
    const unsigned short* __restrict__ wbh, const unsigned short* __restrict__ wbm,
    const unsigned short* __restrict__ wbl,
    float* __restrict__ vst, float* __restrict__ ist,
    unsigned short* __restrict__ zpool, float* __restrict__ partial, int t)
{
  constexpr int THREADS = 256;
  constexpr int BM = MF*16;
  constexpr int BN = 64;
  constexpr int ROWS = BM/WI;
  constexpr int SLOTW = WI+2;
  constexpr int SLOTS = (ROWS+2)*SLOTW;
  constexpr int CPH = CIN_A/64;
  constexpr int S = 9*CPH*2;             // K=32 stages per (half-)K
  constexpr int MT_PER_B = (HIM*WI)/BM;
  constexpr int ACH = CIN_A/8;
  constexpr int ACHUNKS = SLOTS*ACH;
  constexpr int ABYTES = SLOTS*CIN_A*2;
  constexpr int ZBYTES = POOLZ ? BM*BN*2 : 16;
  constexpr int LDSB = ABYTES > ZBYTES ? ABYTES : ZBYTES;
  static_assert(LDSB <= 32*1024, "LDS");

  __shared__ __align__(16) char smem[LDSB];

  int tid = threadIdx.x;
  int rem = blockIdx.x;
  int kh = 0;
  if constexpr (KSPLIT) { kh = rem & 1; rem >>= 1; }
  int nt = 0;
  if constexpr (NT > 1) { nt = rem % NT; rem /= NT; }
  int b = rem / MT_PER_B;
  int y0 = (rem % MT_PER_B) * ROWS;
  int lane = tid & 63, wn = tid >> 6;
  int csrc0 = KSPLIT ? kh*CIN_A : 0;
  int s0 = KSPLIT ? kh*S : 0;

  // ---- stage A tile (once) ----
  for (int ch = tid; ch < ACHUNKS; ch += THREADS) {
    int slot = ch / ACH, g = ch % ACH;
    int yr = slot / SLOTW, xr = slot % SLOTW;
    int y = y0 + yr - 1, xg = xr - 1;
    u32x4 val; val[0]=0; val[1]=0; val[2]=0; val[3]=0;
    if (y >= 0 && y < HIM && xg >= 0 && xg < WI)
      val = *(const u32x4*)(zsrc + ((long)(b*HIM + y)*WI + xg)*CIN_SRC + csrc0 + g*8);
    int addr = ((slot*CIN_A + g*8)*2) ^ ((slot & 7) << 4);
    *(u32x4*)(smem + addr) = val;
  }

  // ---- B: per-lane fragment loads from fragment-major global layout ----
  struct B3 { short8 h, m, l; };
  int kg = lane >> 4;
  int co_g = nt*BN + wn*16 + (lane & 15);
  auto loadB = [&](int sg) {
    B3 r;
    long off = ((long)(sg*4 + kg)*COUT + co_g)*8;
    r.h = *(const short8*)(wbh + off);
    r.m = *(const short8*)(wbm + off);
    r.l = *(const short8*)(wbl + off);
    return r;
  };

  f32x4 acc[MF];
#pragma unroll
  for (int mf = 0; mf < MF; mf++) {
    acc[mf][0]=0.f; acc[mf][1]=0.f; acc[mf][2]=0.f; acc[mf][3]=0.f;
  }

  B3 b0 = loadB(s0);
  B3 b1 = loadB(s0 + 1);
  __syncthreads();

  // ---- barrier-free K loop, depth-2 register prefetch, fully unrolled ----
#pragma unroll
  for (int s = 0; s < S; s++) {
    B3 b2 = b1;
    if (s + 2 < S) b2 = loadB(s0 + s + 2);
    int p = s >> 1, ks = s & 1;
    int tap = p / CPH, cs = p % CPH;
    int dy = tap/3 - 1, dx = tap%3 - 1;
    int choff2 = (cs*64 + ks*32 + kg*8)*2;
    short8 a[MF];
#pragma unroll
    for (int mf = 0; mf < MF; mf++) {
      int pl = mf*16 + (lane & 15);
      int yl = pl / WI, xl = pl % WI;
      int slot = (yl + dy + 1)*SLOTW + (xl + dx + 1);
      int addr = ((slot*CIN_A)*2 + choff2) ^ ((slot & 7) << 4);
      a[mf] = *(const short8*)(smem + addr);
    }
#pragma unroll
    for (int mf = 0; mf < MF; mf++)
      acc[mf] = __builtin_amdgcn_mfma_f32_16x16x32_bf16(a[mf], b0.h, acc[mf], 0, 0, 0);
#pragma unroll
    for (int mf = 0; mf < MF; mf++)
      acc[mf] = __builtin_amdgcn_mfma_f32_16x16x32_bf16(a[mf], b0.m, acc[mf], 0, 0, 0);
#pragma unroll
    for (int mf = 0; mf < MF; mf++)
      acc[mf] = __builtin_amdgcn_mfma_f32_16x16x32_bf16(a[mf], b0.l, acc[mf], 0, 0, 0);
    b0 = b1; b1 = b2;
  }

  // ---- epilogue: LIF state update (+ z into LDS for pooling) ----
  if constexpr (POOLZ) __syncthreads();   // A-LDS dead; reuse as z buffer
  unsigned short* zb = (unsigned short*)smem;
  int mbase = (b*HIM + y0)*WI;
  int chn = wn*16 + (lane & 15);
  int chg = nt*BN + chn;
#pragma unroll
  for (int mf = 0; mf < MF; mf++) {
#pragma unroll
    for (int r = 0; r < 4; r++) {
      int pix = mf*16 + (lane >> 4)*4 + r;
      long idx = (long)(mbase + pix)*COUT + chg;
      float cv = acc[mf][r];
      if constexpr (KSPLIT) {
        atomicAdd(partial + idx, cv);
      } else {
        float vv = 0.f, ii = 0.f;
        if (t != 0) { vv = vst[idx]; ii = ist[idx]; }
        float vdec = vv + DTM*((0.0f - vv) + ii);
        bool z = (vdec - VTH) > 0.0f;
        vst[idx] = z ? 0.0f : vdec;
        ist[idx] = SYN*ii + cv;
        if constexpr (POOLZ) zb[pix*BN + chn] = z ? 0x3F80 : 0;
      }
    }
  }

  // ---- fused 2x2 max-pool of spikes (binary max == OR), coalesced write ----
  if constexpr (POOLZ) {
    __syncthreads();
    constexpr int WP = WI/2, PR = ROWS/2, CH16 = BN/8;
    for (int c = tid; c < PR*WP*CH16; c += THREADS) {
      int ppx = c / CH16, ck = c % CH16;
      int py = ppx / WP, px = ppx % WP;
      int b0_ = ((2*py)*WI + 2*px)*BN + ck*8;
      u32x4 q0 = *(const u32x4*)(zb + b0_);
      u32x4 q1 = *(const u32x4*)(zb + b0_ + BN);
      u32x4 q2 = *(const u32x4*)(zb + b0_ + WI*BN);
      u32x4 q3 = *(const u32x4*)(zb + b0_ + WI*BN + BN);
      u32x4 vo = (q0|q1)|(q2|q3);
      long g = ((long)(b*(HIM/2) + (y0>>1) + py)*WP + px)*COUT + nt*BN + ck*8;
      *(u32x4*)(zpool + g) = vo;
    }
  }
}

// ---------------------------------------------------------------------------
// K5: LIF4 (from conv4 partial) + 2x2 pool + FC(4096->10) + LI + noise + max.
// 512 threads, one block per image. Re-zeroes partial for the next step.
// ---------------------------------------------------------------------------
__global__ __launch_bounds__(512) void k5_lif4_fc(
    float* __restrict__ partial, float* __restrict__ v4, float* __restrict__ i4,
    const float* __restrict__ wfc, const float* __restrict__ noise,
    float* __restrict__ vl, float* __restrict__ il, float* __restrict__ dout, int t)
{
  __shared__ unsigned zbits[64][8];
  __shared__ unsigned pb[16][8];
  __shared__ float red[8][10];
  int tid = threadIdx.x, b = blockIdx.x;
  int px = tid >> 3, c8 = tid & 7;      // 64 px x 8 groups of 32 ch
  long base = ((long)b*64 + px)*256 + c8*32;
  unsigned mask = 0u;
#pragma unroll
  for (int q = 0; q < 8; q++) {
    float4 pv = *(const float4*)(partial + base + q*4);
    float vv[4] = {0.f,0.f,0.f,0.f}, ii[4] = {0.f,0.f,0.f,0.f};
    if (t != 0) {
      float4 v4v = *(const float4*)(v4 + base + q*4);
      float4 i4v = *(const float4*)(i4 + base + q*4);
      vv[0]=v4v.x; vv[1]=v4v.y; vv[2]=v4v.z; vv[3]=v4v.w;
      ii[0]=i4v.x; ii[1]=i4v.y; ii[2]=i4v.z; ii[3]=i4v.w;
    }
    float cv[4] = {pv.x, pv.y, pv.z, pv.w};
#pragma unroll
    for (int s = 0; s < 4; s++) {
      float vdec = vv[s] + DTM*((0.0f - vv[s]) + ii[s]);
      bool z = (vdec - VTH) > 0.0f;
      vv[s] = z ? 0.0f : vdec;
      ii[s] = SYN*ii[s] + cv[s];
      if (z) mask |= (1u << (q*4 + s));
    }
    *(float4*)(v4 + base + q*4) = make_float4(vv[0],vv[1],vv[2],vv[3]);
    *(float4*)(i4 + base + q*4) = make_float4(ii[0],ii[1],ii[2],ii[3]);
    *(float4*)(partial + base + q*4) = make_float4(0.f,0.f,0.f,0.f);
  }
  zbits[px][c8] = mask;
  __syncthreads();
  if (tid < 128) {
    int pp = tid >> 3, grp = tid & 7;
    int py = pp >> 2, pxx = pp & 3;
    int p00 = (2*py)*8 + 2*pxx;
    pb[pp][grp] = zbits[p00][grp] | zbits[p00+1][grp] | zbits[p00+8][grp] | zbits[p00+9][grp];
  }
  __syncthreads();
  float sums[10];
#pragma unroll
  for (int j = 0; j < 10; j++) sums[j] = 0.f;
#pragma unroll
  for (int q = 0; q < 8; q++) {
    int k = q*512 + tid;
    int c = k >> 4, s = k & 15;
    if ((pb[s][c >> 5] >> (c & 31)) & 1u) {
#pragma unroll
      for (int j = 0; j < 10; j++) sums[j] += wfc[j*4096 + k];
    }
  }
#pragma unroll
  for (int j = 0; j < 10; j++) {
    float v = sums[j];
    for (int off = 32; off; off >>= 1) v += __shfl_xor(v, off);
    if ((tid & 63) == 0) red[tid >> 6][j] = v;
  }
  __syncthreads();
  if (tid < 10) {
    float o = 0.f;
#pragma unroll
    for (int w = 0; w < 8; w++) o += red[w][tid];
    float vo = 0.f, io = 0.f;
    if (t != 0) { vo = vl[b*10 + tid]; io = il[b*10 + tid]; }
    float vn = vo + DTM*((0.0f - vo) + io);
    float inw = SYN*io + o;
    vl[b*10 + tid] = vn; il[b*10 + tid] = inw;
    float volt = vn + 0.001f*noise[((long)t*32 + b)*10 + tid];
    dout[b*10 + tid] = (t == 0) ? volt : fmaxf(dout[b*10 + tid], volt);
  }
}

// ---------------------------------------------------------------------------
extern "C" void kernel_launch(void* const* d_in, const int* in_sizes, int n_in,
                              void* d_out, int out_size, void* d_ws, size_t ws_size,
                              hipStream_t stream)
{
  const float* x     = (const float*)d_in[0];
  const float* noise = (const float*)d_in[1];
  const float* w1    = (const float*)d_in[2];
  const float* w2    = (const float*)d_in[3];
  const float* w3    = (const float*)d_in[4];
  const float* w4    = (const float*)d_in[5];
  const float* wfc   = (const float*)d_in[6];
  float* dout = (float*)d_out;

  char* ws = (char*)d_ws;
  size_t off = 0;
  auto alloc = [&](size_t bytes) -> char* {
    char* p = ws + off;
    off = (off + bytes + 255) & ~(size_t)255;
    return p;
  };
  float* v1 = (float*)alloc(2097152u*4); float* i1 = (float*)alloc(2097152u*4);
  float* v2 = (float*)alloc(4194304u*4); float* i2 = (float*)alloc(4194304u*4);
  float* v3 = (float*)alloc(2097152u*4); float* i3 = (float*)alloc(2097152u*4);
  float* v4 = (float*)alloc(524288u*4);  float* i4 = (float*)alloc(524288u*4);
  unsigned short* z1  = (unsigned short*)alloc(2097152u*2);   // full-res spikes L1
  unsigned short* z2p = (unsigned short*)alloc(1048576u*2);   // pooled spikes L2: [32][16][16][128]
  unsigned short* z3p = (unsigned short*)alloc(524288u*2);    // pooled spikes L3: [32][8][8][256]
  float* partial = (float*)alloc(524288u*4);
  float* vl = (float*)alloc(1280);
  float* il = (float*)alloc(1280);
  unsigned short* wb2h = (unsigned short*)alloc(73728u*2);
  unsigned short* wb2m = (unsigned short*)alloc(73728u*2);
  unsigned short* wb2l = (unsigned short*)alloc(73728u*2);
  unsigned short* wb3h = (unsigned short*)alloc(294912u*2);
  unsigned short* wb3m = (unsigned short*)alloc(294912u*2);
  unsigned short* wb3l = (unsigned short*)alloc(294912u*2);
  unsigned short* wb4h = (unsigned short*)alloc(589824u*2);
  unsigned short* wb4m = (unsigned short*)alloc(589824u*2);
  unsigned short* wb4l = (unsigned short*)alloc(589824u*2);

  prep_kernel<<<5792, 256, 0, stream>>>(w2, w3, w4,
      wb2h, wb2m, wb2l, wb3h, wb3m, wb3l, wb4h, wb4m, wb4l, partial);

  for (int t = 0; t < 16; t++) {
    k1_conv1_lif<<<512, 256, 0, stream>>>(x, w1, v1, i1, z1, t);
    // conv2: 64->128 @32x32, BM=64 BN=64 NT=2, grid 1024 (4 blocks/CU)
    conv_lif<4, 64,32,32,128, 64,2,false,true><<<1024, 256, 0, stream>>>(
        z1, wb2h, wb2m, wb2l, v2, i2, z2p, nullptr, t);
    // conv3: 128->256 @16x16 pooled-in, BM=64 BN=64 NT=4, grid 512
    conv_lif<4,128,16,16,256,128,4,false,true><<<512, 256, 0, stream>>>(
        z2p, wb3h, wb3m, wb3l, v3, i3, z3p, nullptr, t);
    // conv4: 256->256 @8x8 pooled-in, BM=32 BN=64 NT=4 KSPLIT=2, grid 512
    conv_lif<2,128, 8, 8,256,256,4,true,false><<<512, 256, 0, stream>>>(
        z3p, wb4h, wb4m, wb4l, nullptr, nullptr, nullptr, partial, t);
    k5_lif4_fc<<<32, 512, 0, stream>>>(partial, v4, i4, wfc, noise, vl, il, dout, t);
  }
}

// Round 9
// 2263.025 us; speedup vs baseline: 1.0421x; 1.0221x over previous
//
#include <hip/hip_runtime.h>

typedef __attribute__((ext_vector_type(8))) short short8;
typedef __attribute__((ext_vector_type(4))) float f32x4;
typedef __attribute__((ext_vector_type(4))) unsigned int u32x4;

#define DEV static __device__ __forceinline__

DEV unsigned short f2bf(float f){
  unsigned int u = __float_as_uint(f);
  u += 0x7FFFu + ((u >> 16) & 1u);
  return (unsigned short)(u >> 16);
}
DEV float bf2f(unsigned short h){ return __uint_as_float(((unsigned int)h) << 16); }

DEV f32x4 ntload4(const float* p){ return __builtin_nontemporal_load((const f32x4*)p); }
DEV void ntstore4(float* p, f32x4 v){ __builtin_nontemporal_store(v, (f32x4*)p); }

#define DTM 0.1f   /* DT*TAU_MEM_INV */
#define SYN 0.8f   /* 1 - DT*TAU_SYN_INV */
#define VTH 0.2f

// ---------------------------------------------------------------------------
// prep: weights -> MFMA-fragment-major bf16 hi/mid/lo digit layout:
//   dst[((s*4 + kg)*COUT + co)*8 + j] = digit(w[co][ci(s,kg,j)][tap(s)])
// Wave B-fragment load = 16 lanes x contiguous 16B (L2-friendly).
// Also zeroes the conv4 partial buffer.
// ---------------------------------------------------------------------------
__global__ __launch_bounds__(256) void prep_kernel(
    const float* __restrict__ w2, const float* __restrict__ w3, const float* __restrict__ w4,
    unsigned short* __restrict__ wb2h, unsigned short* __restrict__ wb2m, unsigned short* __restrict__ wb2l,
    unsigned short* __restrict__ wb3h, unsigned short* __restrict__ wb3m, unsigned short* __restrict__ wb3l,
    unsigned short* __restrict__ wb4h, unsigned short* __restrict__ wb4m, unsigned short* __restrict__ wb4l,
    float* __restrict__ partial)
{
  const int N2 = 9*128*64, N3 = 9*256*128, N4 = 9*256*256, NP = 2048*256;
  int tid = blockIdx.x*256 + threadIdx.x;
  if (tid < N2) {           // conv2: CIN=64, CPH=1, S=18
    int j = tid & 7, co = (tid >> 3) & 127, q = (tid >> 3) >> 7;
    int kg = q & 3, s = q >> 2;
    int tap = s >> 1, ks = s & 1;
    int ci = ks*32 + kg*8 + j;
    float w = w2[(co*64 + ci)*9 + tap];
    unsigned short h = f2bf(w);   float r1 = w - bf2f(h);
    unsigned short m = f2bf(r1);  float r2 = r1 - bf2f(m);
    wb2h[tid] = h; wb2m[tid] = m; wb2l[tid] = f2bf(r2);
    return;
  }
  tid -= N2;
  if (tid < N3) {           // conv3: CIN=128, CPH=2, S=36
    int j = tid & 7, co = (tid >> 3) & 255, q = (tid >> 3) >> 8;
    int kg = q & 3, s = q >> 2;
    int p = s >> 1, ks = s & 1, tap = p >> 1, cs = p & 1;
    int ci = cs*64 + ks*32 + kg*8 + j;
    float w = w3[(co*128 + ci)*9 + tap];
    unsigned short h = f2bf(w);   float r1 = w - bf2f(h);
    unsigned short m = f2bf(r1);  float r2 = r1 - bf2f(m);
    wb3h[tid] = h; wb3m[tid] = m; wb3l[tid] = f2bf(r2);
    return;
  }
  tid -= N3;
  if (tid < N4) {           // conv4: CIN=256 as 2 halves of 128, sg in [0,72)
    int j = tid & 7, co = (tid >> 3) & 255, q = (tid >> 3) >> 8;
    int kg = q & 3, sg = q >> 2;
    int hh = sg / 36, sl = sg % 36;
    int p = sl >> 1, ks = sl & 1, tap = p >> 1, cs = p & 1;
    int ci = hh*128 + cs*64 + ks*32 + kg*8 + j;
    float w = w4[(co*256 + ci)*9 + tap];
    unsigned short h = f2bf(w);   float r1 = w - bf2f(h);
    unsigned short m = f2bf(r1);  float r2 = r1 - bf2f(m);
    wb4h[tid] = h; wb4m[tid] = m; wb4l[tid] = f2bf(r2);
    return;
  }
  tid -= N4;
  if (tid < NP) partial[tid] = 0.f;
}

// ---------------------------------------------------------------------------
// K1: conv1 (fp32 direct, 3->64, 3x3 SAME) + LIF1. grid 512 = 32 imgs x 16 row-pairs
// ---------------------------------------------------------------------------
__global__ __launch_bounds__(256) void k1_conv1_lif(
    const float* __restrict__ x, const float* __restrict__ w1,
    float* __restrict__ v1, float* __restrict__ i1,
    unsigned short* __restrict__ z1, int t)
{
  __shared__ float xs[3][4][34];
  __shared__ float wl[27][64];
  int tid = threadIdx.x;
  int b = blockIdx.x >> 4, y0 = (blockIdx.x & 15) * 2;
  for (int e = tid; e < 3*4*34; e += 256) {
    int ci = e/136, r2 = e%136, r = r2/34, xi = r2%34;
    int y = y0 - 1 + r, xg = xi - 1;
    float v = 0.f;
    if (y >= 0 && y < 32 && xg >= 0 && xg < 32)
      v = x[((t*32 + b)*3 + ci)*1024 + y*32 + xg];
    xs[ci][r][xi] = v;
  }
  for (int e = tid; e < 27*64; e += 256) {
    int row = e >> 6, co = e & 63;
    int ci = row % 3, tap = row / 3, ky = tap/3, kx = tap%3;
    wl[row][co] = w1[((co*3+ci)*3+ky)*3+kx];
  }
  __syncthreads();
  int px = tid >> 2, cg = tid & 3;
  int ly = px >> 5, lx = px & 31;
  float acc[16];
#pragma unroll
  for (int q = 0; q < 16; q++) acc[q] = 0.f;
#pragma unroll
  for (int ky = 0; ky < 3; ky++)
#pragma unroll
    for (int kx = 0; kx < 3; kx++)
#pragma unroll
      for (int ci = 0; ci < 3; ci++) {
        float xv = xs[ci][ly+ky][lx+kx];
        const float4* wr = (const float4*)&wl[(ky*3+kx)*3+ci][cg*16];
#pragma unroll
        for (int q = 0; q < 4; q++) {
          float4 w4 = wr[q];
          acc[q*4+0] = fmaf(xv, w4.x, acc[q*4+0]);
          acc[q*4+1] = fmaf(xv, w4.y, acc[q*4+1]);
          acc[q*4+2] = fmaf(xv, w4.z, acc[q*4+2]);
          acc[q*4+3] = fmaf(xv, w4.w, acc[q*4+3]);
        }
      }
  int m_g = b*1024 + (y0+ly)*32 + lx;
  unsigned short zb[16];
#pragma unroll
  for (int q = 0; q < 4; q++) {
    int idx = m_g*64 + cg*16 + q*4;
    float vv[4] = {0.f,0.f,0.f,0.f}, ii[4] = {0.f,0.f,0.f,0.f};
    if (t != 0) {
      float4 v4 = *(const float4*)(v1+idx); float4 i4 = *(const float4*)(i1+idx);
      vv[0]=v4.x; vv[1]=v4.y; vv[2]=v4.z; vv[3]=v4.w;
      ii[0]=i4.x; ii[1]=i4.y; ii[2]=i4.z; ii[3]=i4.w;
    }
#pragma unroll
    for (int s = 0; s < 4; s++) {
      float vdec = vv[s] + DTM*((0.0f - vv[s]) + ii[s]);
      bool z = (vdec - VTH) > 0.0f;
      vv[s] = z ? 0.0f : vdec;
      ii[s] = SYN*ii[s] + acc[q*4+s];
      zb[q*4+s] = z ? 0x3F80 : 0;
    }
    *(float4*)(v1+idx) = make_float4(vv[0],vv[1],vv[2],vv[3]);
    *(float4*)(i1+idx) = make_float4(ii[0],ii[1],ii[2],ii[3]);
  }
  u32x4 za, zc;
  za[0]=zb[0]|((unsigned)zb[1]<<16); za[1]=zb[2]|((unsigned)zb[3]<<16);
  za[2]=zb[4]|((unsigned)zb[5]<<16); za[3]=zb[6]|((unsigned)zb[7]<<16);
  zc[0]=zb[8]|((unsigned)zb[9]<<16); zc[1]=zb[10]|((unsigned)zb[11]<<16);
  zc[2]=zb[12]|((unsigned)zb[13]<<16); zc[3]=zb[14]|((unsigned)zb[15]<<16);
  *(u32x4*)(z1 + m_g*64 + cg*16) = za;
  *(u32x4*)(z1 + m_g*64 + cg*16 + 8) = zc;
}

// ---------------------------------------------------------------------------
// Implicit-GEMM conv (3x3 SAME) over binary spikes, bf16 hi/mid/lo 3-digit
// MFMA. A staged once in LDS (XOR-swizzled); B fragments per-lane from global
// fragment-major layout (L2-resident) with depth-2 register prefetch; K-loop
// has NO barriers. Epilogue re-tiles C through LDS so LIF state v/i are
// read+written as float4 with wave-contiguous 256B bursts (full cache lines),
// nontemporal to keep weights L2-resident. POOLZ: fused 2x2 spike max-pool
// (binary max == OR). KSPLIT: line-local atomic partial accumulation.
// ---------------------------------------------------------------------------
template<int MF, int CIN_A, int WI, int HIM, int COUT, int CIN_SRC,
         int NT, bool KSPLIT, bool POOLZ>
__global__ __launch_bounds__(256, 4) void conv_lif(
    const unsigned short* __restrict__ zsrc,
    const unsigned short* __restrict__ wbh, const unsigned short* __restrict__ wbm,
    const unsigned short* __restrict__ wbl,
    float* __restrict__ vst, float* __restrict__ ist,
    unsigned short* __restrict__ zpool, float* __restrict__ partial, int t)
{
  constexpr int THREADS = 256;
  constexpr int BM = MF*16;
  constexpr int BN = 64;
  constexpr int ROWS = BM/WI;
  constexpr int SLOTW = WI+2;
  constexpr int SLOTS = (ROWS+2)*SLOTW;
  constexpr int CPH = CIN_A/64;
  constexpr int S = 9*CPH*2;             // K=32 stages per (half-)K
  constexpr int MT_PER_B = (HIM*WI)/BM;
  constexpr int ACH = CIN_A/8;
  constexpr int ACHUNKS = SLOTS*ACH;
  constexpr int ABYTES = SLOTS*CIN_A*2;
  constexpr int CBYTES = BM*BN*4;
  constexpr int ZBYTES = POOLZ ? BM*BN*2 : 0;
  constexpr int EBYTES = CBYTES + ZBYTES;
  constexpr int LDSB = ABYTES > EBYTES ? ABYTES : EBYTES;
  static_assert(LDSB <= 32*1024, "LDS");

  __shared__ __align__(16) char smem[LDSB];

  int tid = threadIdx.x;
  int rem = blockIdx.x;
  int kh = 0;
  if constexpr (KSPLIT) { kh = rem & 1; rem >>= 1; }
  int nt = 0;
  if constexpr (NT > 1) { nt = rem % NT; rem /= NT; }
  int b = rem / MT_PER_B;
  int y0 = (rem % MT_PER_B) * ROWS;
  int lane = tid & 63, wn = tid >> 6;
  int csrc0 = KSPLIT ? kh*CIN_A : 0;
  int s0 = KSPLIT ? kh*S : 0;

  // ---- stage A tile (once) ----
  for (int ch = tid; ch < ACHUNKS; ch += THREADS) {
    int slot = ch / ACH, g = ch % ACH;
    int yr = slot / SLOTW, xr = slot % SLOTW;
    int y = y0 + yr - 1, xg = xr - 1;
    u32x4 val; val[0]=0; val[1]=0; val[2]=0; val[3]=0;
    if (y >= 0 && y < HIM && xg >= 0 && xg < WI)
      val = *(const u32x4*)(zsrc + ((long)(b*HIM + y)*WI + xg)*CIN_SRC + csrc0 + g*8);
    int addr = ((slot*CIN_A + g*8)*2) ^ ((slot & 7) << 4);
    *(u32x4*)(smem + addr) = val;
  }

  // ---- B: per-lane fragment loads from fragment-major global layout ----
  struct B3 { short8 h, m, l; };
  int kg = lane >> 4;
  int co_g = nt*BN + wn*16 + (lane & 15);
  auto loadB = [&](int sg) {
    B3 r;
    long off = ((long)(sg*4 + kg)*COUT + co_g)*8;
    r.h = *(const short8*)(wbh + off);
    r.m = *(const short8*)(wbm + off);
    r.l = *(const short8*)(wbl + off);
    return r;
  };

  f32x4 acc[MF];
#pragma unroll
  for (int mf = 0; mf < MF; mf++) {
    acc[mf][0]=0.f; acc[mf][1]=0.f; acc[mf][2]=0.f; acc[mf][3]=0.f;
  }

  B3 b0 = loadB(s0);
  B3 b1 = loadB(s0 + 1);
  __syncthreads();

  // ---- barrier-free K loop, depth-2 register prefetch, fully unrolled ----
#pragma unroll
  for (int s = 0; s < S; s++) {
    B3 b2 = b1;
    if (s + 2 < S) b2 = loadB(s0 + s + 2);
    int p = s >> 1, ks = s & 1;
    int tap = p / CPH, cs = p % CPH;
    int dy = tap/3 - 1, dx = tap%3 - 1;
    int choff2 = (cs*64 + ks*32 + kg*8)*2;
    short8 a[MF];
#pragma unroll
    for (int mf = 0; mf < MF; mf++) {
      int pl = mf*16 + (lane & 15);
      int yl = pl / WI, xl = pl % WI;
      int slot = (yl + dy + 1)*SLOTW + (xl + dx + 1);
      int addr = ((slot*CIN_A)*2 + choff2) ^ ((slot & 7) << 4);
      a[mf] = *(const short8*)(smem + addr);
    }
#pragma unroll
    for (int mf = 0; mf < MF; mf++)
      acc[mf] = __builtin_amdgcn_mfma_f32_16x16x32_bf16(a[mf], b0.h, acc[mf], 0, 0, 0);
#pragma unroll
    for (int mf = 0; mf < MF; mf++)
      acc[mf] = __builtin_amdgcn_mfma_f32_16x16x32_bf16(a[mf], b0.m, acc[mf], 0, 0, 0);
#pragma unroll
    for (int mf = 0; mf < MF; mf++)
      acc[mf] = __builtin_amdgcn_mfma_f32_16x16x32_bf16(a[mf], b0.l, acc[mf], 0, 0, 0);
    b0 = b1; b1 = b2;
  }

  // ---- epilogue: re-tile C via LDS -> coalesced float4 LIF state I/O ----
  __syncthreads();                       // A-LDS dead; reuse
  float* cb = (float*)smem;              // [BM][BN] fp32, XOR-swizzled
  unsigned short* zb = (unsigned short*)(smem + CBYTES);  // [BM][BN] u16
  {
    int chn = wn*16 + (lane & 15);
#pragma unroll
    for (int mf = 0; mf < MF; mf++)
#pragma unroll
      for (int r = 0; r < 4; r++) {
        int pix = mf*16 + (lane >> 4)*4 + r;
        cb[pix*BN + (chn ^ ((pix & 3) << 4))] = acc[mf][r];
      }
  }
  __syncthreads();
  constexpr int ITER = (BM*BN/4)/THREADS;
  int mbase = (b*HIM + y0)*WI;
#pragma unroll
  for (int k = 0; k < ITER; k++) {
    int e = k*THREADS + tid;
    int row = e >> 4;                    // BN/4 = 16 float4 per row
    int ch  = (e & 15) << 2;
    f32x4 cv = *(const f32x4*)&cb[row*BN + (ch ^ ((row & 3) << 4))];
    long gidx = (long)(mbase + row)*COUT + nt*BN + ch;
    if constexpr (KSPLIT) {
      atomicAdd(partial + gidx + 0, cv[0]);
      atomicAdd(partial + gidx + 1, cv[1]);
      atomicAdd(partial + gidx + 2, cv[2]);
      atomicAdd(partial + gidx + 3, cv[3]);
    } else {
      f32x4 vv = {0.f,0.f,0.f,0.f}, ii = {0.f,0.f,0.f,0.f};
      if (t != 0) { vv = ntload4(vst + gidx); ii = ntload4(ist + gidx); }
      unsigned short zs[4];
#pragma unroll
      for (int s = 0; s < 4; s++) {
        float vdec = vv[s] + DTM*((0.0f - vv[s]) + ii[s]);
        bool z = (vdec - VTH) > 0.0f;
        vv[s] = z ? 0.0f : vdec;
        ii[s] = SYN*ii[s] + cv[s];
        zs[s] = z ? 0x3F80 : 0;
      }
      ntstore4(vst + gidx, vv);
      ntstore4(ist + gidx, ii);
      if constexpr (POOLZ)
        *(ushort4*)&zb[row*BN + ch] = make_ushort4(zs[0],zs[1],zs[2],zs[3]);
    }
  }

  // ---- fused 2x2 max-pool of spikes (binary max == OR), coalesced write ----
  if constexpr (POOLZ) {
    __syncthreads();
    constexpr int WP = WI/2, PR = ROWS/2, CH16 = BN/8;
    for (int c = tid; c < PR*WP*CH16; c += THREADS) {
      int ppx = c / CH16, ck = c % CH16;
      int py = ppx / WP, px = ppx % WP;
      int b0_ = ((2*py)*WI + 2*px)*BN + ck*8;
      u32x4 q0 = *(const u32x4*)(zb + b0_);
      u32x4 q1 = *(const u32x4*)(zb + b0_ + BN);
      u32x4 q2 = *(const u32x4*)(zb + b0_ + WI*BN);
      u32x4 q3 = *(const u32x4*)(zb + b0_ + WI*BN + BN);
      u32x4 vo = (q0|q1)|(q2|q3);
      long g = ((long)(b*(HIM/2) + (y0>>1) + py)*WP + px)*COUT + nt*BN + ck*8;
      *(u32x4*)(zpool + g) = vo;
    }
  }
}

// ---------------------------------------------------------------------------
// K5: LIF4 (from conv4 partial) + 2x2 pool + FC(4096->10) + LI + noise + max.
// 512 threads, one block per image. Re-zeroes partial for the next step.
// ---------------------------------------------------------------------------
__global__ __launch_bounds__(512) void k5_lif4_fc(
    float* __restrict__ partial, float* __restrict__ v4, float* __restrict__ i4,
    const float* __restrict__ wfc, const float* __restrict__ noise,
    float* __restrict__ vl, float* __restrict__ il, float* __restrict__ dout, int t)
{
  __shared__ unsigned zbits[64][8];
  __shared__ unsigned pb[16][8];
  __shared__ float red[8][10];
  int tid = threadIdx.x, b = blockIdx.x;
  int px = tid >> 3, c8 = tid & 7;      // 64 px x 8 groups of 32 ch
  long base = ((long)b*64 + px)*256 + c8*32;
  unsigned mask = 0u;
#pragma unroll
  for (int q = 0; q < 8; q++) {
    float4 pv = *(const float4*)(partial + base + q*4);
    float vv[4] = {0.f,0.f,0.f,0.f}, ii[4] = {0.f,0.f,0.f,0.f};
    if (t != 0) {
      float4 v4v = *(const float4*)(v4 + base + q*4);
      float4 i4v = *(const float4*)(i4 + base + q*4);
      vv[0]=v4v.x; vv[1]=v4v.y; vv[2]=v4v.z; vv[3]=v4v.w;
      ii[0]=i4v.x; ii[1]=i4v.y; ii[2]=i4v.z; ii[3]=i4v.w;
    }
    float cv[4] = {pv.x, pv.y, pv.z, pv.w};
#pragma unroll
    for (int s = 0; s < 4; s++) {
      float vdec = vv[s] + DTM*((0.0f - vv[s]) + ii[s]);
      bool z = (vdec - VTH) > 0.0f;
      vv[s] = z ? 0.0f : vdec;
      ii[s] = SYN*ii[s] + cv[s];
      if (z) mask |= (1u << (q*4 + s));
    }
    *(float4*)(v4 + base + q*4) = make_float4(vv[0],vv[1],vv[2],vv[3]);
    *(float4*)(i4 + base + q*4) = make_float4(ii[0],ii[1],ii[2],ii[3]);
    *(float4*)(partial + base + q*4) = make_float4(0.f,0.f,0.f,0.f);
  }
  zbits[px][c8] = mask;
  __syncthreads();
  if (tid < 128) {
    int pp = tid >> 3, grp = tid & 7;
    int py = pp >> 2, pxx = pp & 3;
    int p00 = (2*py)*8 + 2*pxx;
    pb[pp][grp] = zbits[p00][grp] | zbits[p00+1][grp] | zbits[p00+8][grp] | zbits[p00+9][grp];
  }
  __syncthreads();
  float sums[10];
#pragma unroll
  for (int j = 0; j < 10; j++) sums[j] = 0.f;
#pragma unroll
  for (int q = 0; q < 8; q++) {
    int k = q*512 + tid;
    int c = k >> 4, s = k & 15;
    if ((pb[s][c >> 5] >> (c & 31)) & 1u) {
#pragma unroll
      for (int j = 0; j < 10; j++) sums[j] += wfc[j*4096 + k];
    }
  }
#pragma unroll
  for (int j = 0; j < 10; j++) {
    float v = sums[j];
    for (int off = 32; off; off >>= 1) v += __shfl_xor(v, off);
    if ((tid & 63) == 0) red[tid >> 6][j] = v;
  }
  __syncthreads();
  if (tid < 10) {
    float o = 0.f;
#pragma unroll
    for (int w = 0; w < 8; w++) o += red[w][tid];
    float vo = 0.f, io = 0.f;
    if (t != 0) { vo = vl[b*10 + tid]; io = il[b*10 + tid]; }
    float vn = vo + DTM*((0.0f - vo) + io);
    float inw = SYN*io + o;
    vl[b*10 + tid] = vn; il[b*10 + tid] = inw;
    float volt = vn + 0.001f*noise[((long)t*32 + b)*10 + tid];
    dout[b*10 + tid] = (t == 0) ? volt : fmaxf(dout[b*10 + tid], volt);
  }
}

// ---------------------------------------------------------------------------
extern "C" void kernel_launch(void* const* d_in, const int* in_sizes, int n_in,
                              void* d_out, int out_size, void* d_ws, size_t ws_size,
                              hipStream_t stream)
{
  const float* x     = (const float*)d_in[0];
  const float* noise = (const float*)d_in[1];
  const float* w1    = (const float*)d_in[2];
  const float* w2    = (const float*)d_in[3];
  const float* w3    = (const float*)d_in[4];
  const float* w4    = (const float*)d_in[5];
  const float* wfc   = (const float*)d_in[6];
  float* dout = (float*)d_out;

  char* ws = (char*)d_ws;
  size_t off = 0;
  auto alloc = [&](size_t bytes) -> char* {
    char* p = ws + off;
    off = (off + bytes + 255) & ~(size_t)255;
    return p;
  };
  float* v1 = (float*)alloc(2097152u*4); float* i1 = (float*)alloc(2097152u*4);
  float* v2 = (float*)alloc(4194304u*4); float* i2 = (float*)alloc(4194304u*4);
  float* v3 = (float*)alloc(2097152u*4); float* i3 = (float*)alloc(2097152u*4);
  float* v4 = (float*)alloc(524288u*4);  float* i4 = (float*)alloc(524288u*4);
  unsigned short* z1  = (unsigned short*)alloc(2097152u*2);   // full-res spikes L1
  unsigned short* z2p = (unsigned short*)alloc(1048576u*2);   // pooled spikes L2: [32][16][16][128]
  unsigned short* z3p = (unsigned short*)alloc(524288u*2);    // pooled spikes L3: [32][8][8][256]
  float* partial = (float*)alloc(524288u*4);
  float* vl = (float*)alloc(1280);
  float* il = (float*)alloc(1280);
  unsigned short* wb2h = (unsigned short*)alloc(73728u*2);
  unsigned short* wb2m = (unsigned short*)alloc(73728u*2);
  unsigned short* wb2l = (unsigned short*)alloc(73728u*2);
  unsigned short* wb3h = (unsigned short*)alloc(294912u*2);
  unsigned short* wb3m = (unsigned short*)alloc(294912u*2);
  unsigned short* wb3l = (unsigned short*)alloc(294912u*2);
  unsigned short* wb4h = (unsigned short*)alloc(589824u*2);
  unsigned short* wb4m = (unsigned short*)alloc(589824u*2);
  unsigned short* wb4l = (unsigned short*)alloc(589824u*2);

  prep_kernel<<<5792, 256, 0, stream>>>(w2, w3, w4,
      wb2h, wb2m, wb2l, wb3h, wb3m, wb3l, wb4h, wb4m, wb4l, partial);

  for (int t = 0; t < 16; t++) {
    k1_conv1_lif<<<512, 256, 0, stream>>>(x, w1, v1, i1, z1, t);
    // conv2: 64->128 @32x32, BM=64 BN=64 NT=2, grid 1024 (4 blocks/CU)
    conv_lif<4, 64,32,32,128, 64,2,false,true><<<1024, 256, 0, stream>>>(
        z1, wb2h, wb2m, wb2l, v2, i2, z2p, nullptr, t);
    // conv3: 128->256 @16x16 pooled-in, BM=32 BN=64 NT=4, grid 1024 (4 blocks/CU)
    conv_lif<2,128,16,16,256,128,4,false,true><<<1024, 256, 0, stream>>>(
        z2p, wb3h, wb3m, wb3l, v3, i3, z3p, nullptr, t);
    // conv4: 256->256 @8x8 pooled-in, BM=32 BN=64 NT=4 KSPLIT=2, grid 512
    conv_lif<2,128, 8, 8,256,256,4,true,false><<<512, 256, 0, stream>>>(
        z3p, wb4h, wb4m, wb4l, nullptr, nullptr, nullptr, partial, t);
    k5_lif4_fc<<<32, 512, 0, stream>>>(partial, v4, i4, wfc, noise, vl, il, dout, t);
  }
}